// Round 8
// baseline (345.985 us; speedup 1.0000x reference)
//
#include <hip/hip_runtime.h>

typedef __bf16 bf16x8 __attribute__((ext_vector_type(8)));
typedef float f32x4 __attribute__((ext_vector_type(4)));
typedef unsigned short ushort8v __attribute__((ext_vector_type(8)));

#define NB 16
#define NT 4096
#define NV 32000
#define ND 512
#define NH 1024
#define NSLOTS 256

__device__ __forceinline__ float b2f(unsigned short u) {
  unsigned int x = ((unsigned int)u) << 16;
  return __builtin_bit_cast(float, x);
}
__device__ __forceinline__ unsigned short f2b(float f) {
  unsigned int x = __builtin_bit_cast(unsigned int, f);
  unsigned int r = (x + 0x7FFFu + ((x >> 16) & 1u)) >> 16;
  return (unsigned short)r;
}

#define GLOAD_LDS16(g, l)                                                              \
  __builtin_amdgcn_global_load_lds((const __attribute__((address_space(1))) void*)(g), \
                                   (__attribute__((address_space(3))) void*)(l), 16, 0, 0)

// ---------------------------------------------------------------------------
// Fused elementwise prep: emb f32->bf16 (blocks <8000) and w1/w2 transpose+cvt.
// ---------------------------------------------------------------------------
__global__ __launch_bounds__(256) void cvtwt_kernel(
    const float* __restrict__ emb, unsigned short* __restrict__ embb,
    const float* __restrict__ w1, const float* __restrict__ w2,
    unsigned short* __restrict__ w1t, unsigned short* __restrict__ w2t) {
  const int blk = blockIdx.x;
  if (blk < 8000) {
    const long base = ((long)blk * 256 + threadIdx.x) * 8;
    float4 a = *(const float4*)&emb[base];
    float4 b = *(const float4*)&emb[base + 4];
    ushort8v o;
    o[0] = f2b(a.x); o[1] = f2b(a.y); o[2] = f2b(a.z); o[3] = f2b(a.w);
    o[4] = f2b(b.x); o[5] = f2b(b.y); o[6] = f2b(b.z); o[7] = f2b(b.w);
    *(ushort8v*)&embb[base] = o;
  } else {
    const int i = (blk - 8000) * 256 + threadIdx.x;
    if (i < ND * NH) {
      const int n = i >> 9, k = i & 511;
      w1t[i] = f2b(w1[k * NH + n]);
    } else {
      const int j = i - ND * NH;
      const int n = j >> 10, k = j & 1023;
      w2t[j] = f2b(w2[k * ND + n]);
    }
  }
}

// ---------------------------------------------------------------------------
// 256x256 bf16 MFMA GEMM: Out = act(A @ Bt^T + bias) -> bf16.
// 8 waves (2M x 4N), per-wave 128x64 output, BK=32, 2-deep LDS double buffer
// (64 KiB total -> 2 blocks/CU for inter-block pipe overlap), (row&3) XOR
// chunk swizzle (both-sides), XCD block swizzle, setprio MFMA clusters.
// K-accumulation order per acc element identical to BK=64 version.
// ---------------------------------------------------------------------------
template <int KDIM, int NLD, int NBN, bool GATHER, bool RELU>
__global__ __launch_bounds__(512, 2) void gemm256_kernel(
    const int* __restrict__ seq, const unsigned short* __restrict__ Abase,
    const unsigned short* __restrict__ Bt, const float* __restrict__ bias,
    unsigned short* __restrict__ Out) {
  extern __shared__ unsigned short smraw[];  // [buf][A 8192 | B 8192] shorts
  const int tid = threadIdx.x;
  const int lane = tid & 63;
  const int w = tid >> 6;   // 0..7
  const int wm = w >> 2;    // 0..1
  const int wn = w & 3;     // 0..3

  const int id = blockIdx.x;
  const int swz = (id & 7) * (gridDim.x >> 3) + (id >> 3);
  const int bm = swz / NBN;
  const int bn = swz % NBN;

  // Staging: tile = 256 rows x 4 chunks(16B) = 1024 chunks per matrix.
  // Inst (w, i): c_lin = (w*2+i)*64 + lane -> row = c_lin>>2, dst chunk =
  // c_lin&3 (HW-linear). LDS slot (row,c) holds global chunk c ^ (row&3).
  const unsigned short* aSrc[2];
  const unsigned short* bSrc[2];
#pragma unroll
  for (int i = 0; i < 2; ++i) {
    const int clin = (w * 2 + i) * 64 + lane;
    const int row = clin >> 2;
    const int sc = (clin & 3) ^ (row & 3);
    long arowg;
    if constexpr (GATHER)
      arowg = seq[bm * 256 + row];
    else
      arowg = bm * 256 + row;
    aSrc[i] = Abase + (size_t)arowg * KDIM + sc * 8;
    bSrc[i] = Bt + (size_t)(bn * 256 + row) * KDIM + sc * 8;
  }

  const int fr = lane & 15;
  const int hi = lane >> 4;
  const int ccd = (hi ^ (fr & 3)) * 8;  // swizzled chunk on read side

  f32x4 acc[8][4] = {};

  auto stage = [&](int buf, int kt) {
    unsigned short* A = smraw + buf * 16384;
    unsigned short* B = A + 8192;
#pragma unroll
    for (int i = 0; i < 2; ++i) {
      GLOAD_LDS16(aSrc[i] + kt * 32, &A[(w * 2 + i) * 512]);
      GLOAD_LDS16(bSrc[i] + kt * 32, &B[(w * 2 + i) * 512]);
    }
  };

  constexpr int NKT = KDIM / 32;
  stage(0, 0);
  __syncthreads();  // drain prologue stage
  int cur = 0;
  for (int kt = 0; kt < NKT; ++kt) {
    if (kt + 1 < NKT) stage(cur ^ 1, kt + 1);  // issue early; drains at loop-end sync
    const unsigned short* A = smraw + cur * 16384;
    const unsigned short* B = A + 8192;
    bf16x8 af[8], bf[4];
#pragma unroll
    for (int m = 0; m < 8; ++m)
      af[m] = __builtin_bit_cast(bf16x8,
               *(const ushort8v*)&A[(wm * 128 + m * 16 + fr) * 32 + ccd]);
#pragma unroll
    for (int n = 0; n < 4; ++n)
      bf[n] = __builtin_bit_cast(bf16x8,
               *(const ushort8v*)&B[(wn * 64 + n * 16 + fr) * 32 + ccd]);
    __builtin_amdgcn_s_setprio(1);
#pragma unroll
    for (int m = 0; m < 8; ++m)
#pragma unroll
      for (int n = 0; n < 4; ++n)
        acc[m][n] = __builtin_amdgcn_mfma_f32_16x16x32_bf16(af[m], bf[n], acc[m][n], 0, 0, 0);
    __builtin_amdgcn_s_setprio(0);
    __syncthreads();  // drains stage kt+1; WAR-protects buf[cur^1]
    cur ^= 1;
  }

  // Epilogue: bias (+relu); repack through LDS [64][264] in four row-quarters.
  float bb[4];
#pragma unroll
  for (int n = 0; n < 4; ++n) bb[n] = bias[bn * 256 + wn * 64 + n * 16 + fr];
  unsigned short* C = smraw;
#pragma unroll
  for (int h = 0; h < 4; ++h) {
    if (h) __syncthreads();  // previous quarter's copy done before overwrite
    if (wm == (h >> 1)) {
      const int mstart = (h & 1) * 4;
#pragma unroll
      for (int mm = 0; mm < 4; ++mm)
#pragma unroll
        for (int n = 0; n < 4; ++n)
#pragma unroll
          for (int i = 0; i < 4; ++i) {
            float v = acc[mstart + mm][n][i] + bb[n];
            if constexpr (RELU) v = fmaxf(v, 0.f);
            C[(mm * 16 + hi * 4 + i) * 264 + wn * 64 + n * 16 + fr] = f2b(v);
          }
    }
    __syncthreads();
#pragma unroll
    for (int it = 0; it < 4; ++it) {
      const int idx = it * 512 + tid;
      const int lrow = idx >> 5;
      const int pos = idx & 31;
      ushort8v v = *(const ushort8v*)&C[lrow * 264 + pos * 8];
      *(ushort8v*)&Out[(size_t)(bm * 256 + h * 64 + lrow) * (size_t)NLD + bn * 256 + pos * 8] = v;
    }
  }
}

// ---------------------------------------------------------------------------
// Fused residual + LayerNorm + gate (f32 math).
// ---------------------------------------------------------------------------
__global__ __launch_bounds__(256) void ln_gate_kernel(
    const int* __restrict__ seq, const float* __restrict__ emb,
    const unsigned short* __restrict__ FF, unsigned short* __restrict__ H,
    const float* __restrict__ ln_g, const float* __restrict__ ln_b,
    const float* __restrict__ wg, const float* __restrict__ bgp,
    float* __restrict__ gate, float* __restrict__ hlast) {
  const int lane = threadIdx.x & 63;
  const int w = threadIdx.x >> 6;
  const int t = blockIdx.x * 4 + w;
  const float* er = emb + (size_t)seq[t] * ND + lane * 8;
  ushort8v fv = *(const ushort8v*)&FF[(size_t)t * ND + lane * 8];
  float4 e0 = *(const float4*)er, e1 = *(const float4*)(er + 4);
  float x[8] = {b2f(fv[0]) + e0.x, b2f(fv[1]) + e0.y, b2f(fv[2]) + e0.z, b2f(fv[3]) + e0.w,
                b2f(fv[4]) + e1.x, b2f(fv[5]) + e1.y, b2f(fv[6]) + e1.z, b2f(fv[7]) + e1.w};
  float s = 0.f, sq = 0.f;
#pragma unroll
  for (int j = 0; j < 8; ++j) {
    s += x[j];
    sq += x[j] * x[j];
  }
#pragma unroll
  for (int o = 32; o; o >>= 1) {
    s += __shfl_xor(s, o);
    sq += __shfl_xor(sq, o);
  }
  const float mu = s * (1.f / 512.f);
  const float var = sq * (1.f / 512.f) - mu * mu;
  const float rs = rsqrtf(var + 1e-5f);
  float gd = 0.f;
  float h[8];
  ushort8v hv;
#pragma unroll
  for (int j = 0; j < 8; ++j) {
    const int col = lane * 8 + j;
    h[j] = (x[j] - mu) * rs * ln_g[col] + ln_b[col];
    hv[j] = f2b(h[j]);
    gd += h[j] * wg[col];
  }
  *(ushort8v*)&H[(size_t)t * ND + lane * 8] = hv;
#pragma unroll
  for (int o = 32; o; o >>= 1) gd += __shfl_xor(gd, o);
  if (lane == 0) gate[t] = 1.f / (1.f + expf(-(gd + bgp[0])));
  if ((t & (NT - 1)) == NT - 1) {
    const int b = t >> 12;
    float* hl = hlast + b * ND + lane * 8;
#pragma unroll
    for (int j = 0; j < 8; ++j) hl[j] = h[j];
  }
}

// ---------------------------------------------------------------------------
// Top-256 of 4096 per batch: radix threshold search on positive f32 bits.
// ---------------------------------------------------------------------------
__global__ __launch_bounds__(256) void topk_kernel(const float* __restrict__ gate,
                                                   int* __restrict__ topidx) {
  __shared__ unsigned int keys[NT];
  __shared__ int cnt;
  __shared__ int scan[256];
  const int b = blockIdx.x, tid = threadIdx.x;
  const float* g = gate + (size_t)b * NT;
  for (int i = tid; i < NT; i += 256) keys[i] = __builtin_bit_cast(unsigned int, g[i]);
  __syncthreads();
  unsigned int K = 0u;
  for (int bit = 31; bit >= 0; --bit) {
    const unsigned int cand = K | (1u << bit);
    if (tid == 0) cnt = 0;
    __syncthreads();
    int c = 0;
    for (int i = tid * 16; i < tid * 16 + 16; ++i) c += (keys[i] >= cand) ? 1 : 0;
    if (c) atomicAdd(&cnt, c);
    __syncthreads();
    const int cn = cnt;
    __syncthreads();
    if (cn >= NSLOTS) K = cand;
  }
  int gcnt = 0, ecnt = 0;
  for (int i = tid * 16; i < tid * 16 + 16; ++i) {
    gcnt += (keys[i] > K) ? 1 : 0;
    ecnt += (keys[i] == K) ? 1 : 0;
  }
  scan[tid] = gcnt;
  __syncthreads();
  for (int off = 1; off < 256; off <<= 1) {
    int v2 = (tid >= off) ? scan[tid - off] : 0;
    __syncthreads();
    scan[tid] += v2;
    __syncthreads();
  }
  const int gi = scan[tid];
  const int tot_gt = scan[255];
  __syncthreads();
  scan[tid] = ecnt;
  __syncthreads();
  for (int off = 1; off < 256; off <<= 1) {
    int v2 = (tid >= off) ? scan[tid - off] : 0;
    __syncthreads();
    scan[tid] += v2;
    __syncthreads();
  }
  const int ei = scan[tid];
  int gpos = gi - gcnt;
  int epos = tot_gt + (ei - ecnt);
  int* outp = topidx + b * NSLOTS;
  for (int i = tid * 16; i < tid * 16 + 16; ++i) {
    if (keys[i] > K) {
      outp[gpos++] = i;
    } else if (keys[i] == K) {
      if (epos < NSLOTS) outp[epos] = i;
      epos++;
    }
  }
}

// ---------------------------------------------------------------------------
// qpart[b][s][c] = sum_{d in slice s} hlast[b][d]*wq[d][c]  (+bq when s==0)
// ---------------------------------------------------------------------------
__global__ __launch_bounds__(256) void qpart_kernel(const float* __restrict__ hlast,
                                                    const float* __restrict__ wq,
                                                    const float* __restrict__ bq,
                                                    float* __restrict__ qpart) {
  const int blk = blockIdx.x;
  const int b = blk >> 3, s = blk & 7;
  const int c0 = threadIdx.x;
  const int d0 = s * 64;
  float a0 = 0.f, a1 = 0.f;
#pragma unroll 4
  for (int dd = 0; dd < 64; ++dd) {
    const float hv = hlast[b * ND + d0 + dd];
    a0 += hv * wq[(size_t)(d0 + dd) * ND + c0];
    a1 += hv * wq[(size_t)(d0 + dd) * ND + c0 + 256];
  }
  if (s == 0) {
    a0 += bq[c0];
    a1 += bq[c0 + 256];
  }
  float* qp = qpart + ((size_t)b * 8 + s) * ND;
  qp[c0] = a0;
  qp[c0 + 256] = a1;
}

// ---------------------------------------------------------------------------
// Fused scores + softmax + ctx. 64 blocks = 16 batches x 4 d-chunks of 128.
// ---------------------------------------------------------------------------
__global__ __launch_bounds__(256) void attn_kernel(
    const unsigned short* __restrict__ H, const float* __restrict__ qpart,
    const int* __restrict__ topidx, float* __restrict__ ctx) {
  __shared__ float qs[512];
  __shared__ float attnv[256];
  __shared__ int idxs[256];
  __shared__ float red[4];
  __shared__ float part[2][128];
  const int blk = blockIdx.x;
  const int b = blk >> 2, dc = blk & 3;
  const int tid = threadIdx.x;
  const int lane = tid & 63, wv = tid >> 6;
  {
    float a0 = 0.f, a1 = 0.f;
#pragma unroll
    for (int s = 0; s < 8; ++s) {
      const float* qp = qpart + ((size_t)b * 8 + s) * ND;
      a0 += qp[tid];
      a1 += qp[tid + 256];
    }
    qs[tid] = a0;
    qs[tid + 256] = a1;
  }
  idxs[tid] = topidx[b * 256 + tid];
  __syncthreads();
  const unsigned short* hr = H + ((size_t)b * NT + idxs[tid]) * ND;
  float sc = 0.f;
  for (int d0 = 0; d0 < 512; d0 += 8) {
    ushort8v hv = *(const ushort8v*)&hr[d0];
#pragma unroll
    for (int j = 0; j < 8; ++j) sc += b2f(hv[j]) * qs[d0 + j];
  }
  float m = sc;
#pragma unroll
  for (int o = 32; o; o >>= 1) m = fmaxf(m, __shfl_xor(m, o));
  if (lane == 0) red[wv] = m;
  __syncthreads();
  m = fmaxf(fmaxf(red[0], red[1]), fmaxf(red[2], red[3]));
  __syncthreads();
  const float e = expf(sc - m);
  float ssum = e;
#pragma unroll
  for (int o = 32; o; o >>= 1) ssum += __shfl_xor(ssum, o);
  if (lane == 0) red[wv] = ssum;
  __syncthreads();
  ssum = red[0] + red[1] + red[2] + red[3];
  attnv[tid] = e / ssum;
  __syncthreads();
  const int d = dc * 128 + (tid & 127);
  const int kh = tid >> 7;
  float c = 0.f;
#pragma unroll 4
  for (int k2 = 0; k2 < 128; ++k2) {
    const int k = kh * 128 + k2;
    c += attnv[k] * b2f(H[((size_t)b * NT + idxs[k]) * ND + d]);
  }
  part[kh][tid & 127] = c;
  __syncthreads();
  if (tid < 128) ctx[b * 512 + dc * 128 + tid] = part[0][tid] + part[1][tid];
}

// ---------------------------------------------------------------------------
// Out-projection stage 1: part[s][b][v] = sum_{d in slice s(32)} ctx[b][d]*wo[d][v]
// ---------------------------------------------------------------------------
__global__ __launch_bounds__(256) void out_part_kernel(const float* __restrict__ ctx,
                                                       const float* __restrict__ wo,
                                                       float* __restrict__ part) {
  const int blk = blockIdx.x;
  const int ct = blk % 125, s = blk / 125;
  const int v = ct * 256 + threadIdx.x;
  const int d0 = s * 32;
  const float* wp = wo + (size_t)d0 * NV + v;
  float acc[16] = {};
#pragma unroll 4
  for (int dd = 0; dd < 32; ++dd) {
    const float wv = wp[(size_t)dd * NV];
#pragma unroll
    for (int bb = 0; bb < 16; ++bb) acc[bb] += ctx[bb * ND + d0 + dd] * wv;
  }
  float* pp = part + (size_t)s * NB * NV + v;
#pragma unroll
  for (int bb = 0; bb < 16; ++bb) pp[(size_t)bb * NV] = acc[bb];
}

// ---------------------------------------------------------------------------
// Out-projection stage 2: out[b][v] = sum_s part[s][b][v] + bo[v]
// ---------------------------------------------------------------------------
__global__ __launch_bounds__(256) void out_reduce_kernel(const float* __restrict__ part,
                                                         const float* __restrict__ bo,
                                                         float* __restrict__ out) {
  const int i = blockIdx.x * 256 + threadIdx.x;
  const int b = i / NV;
  const int v = i - b * NV;
  float a = bo[v];
#pragma unroll
  for (int s = 0; s < 16; ++s) a += part[(size_t)s * NB * NV + i];
  out[i] = a;
}

// ---------------------------------------------------------------------------
// Workspace layout (total 194.0 MiB):
//   A1     @ 0        : 128 MiB (gemm1 out). After gemm2: 0..64Mi = H,
//                       64Mi..96.8Mi = out-projection partials.
//   region @ 128 MiB  : 64 MiB — embb (phase 1), then FF bf16 (phase 2)
//   w1t    @ 192 MiB  : 1 MiB — dead after gemm1; aliased by small buffers
//   w2t    @ 193 MiB  : 1 MiB
// ---------------------------------------------------------------------------
extern "C" void kernel_launch(void* const* d_in, const int* in_sizes, int n_in,
                              void* d_out, int out_size, void* d_ws, size_t ws_size,
                              hipStream_t stream) {
  const int* seq = (const int*)d_in[0];
  const float* emb = (const float*)d_in[1];
  const float* w1 = (const float*)d_in[2];
  const float* b1 = (const float*)d_in[3];
  const float* w2 = (const float*)d_in[4];
  const float* b2 = (const float*)d_in[5];
  const float* ln_g = (const float*)d_in[6];
  const float* ln_b = (const float*)d_in[7];
  const float* wg = (const float*)d_in[8];
  const float* bg = (const float*)d_in[9];
  const float* wq = (const float*)d_in[10];
  const float* bq = (const float*)d_in[11];
  const float* wo = (const float*)d_in[12];
  const float* bo = (const float*)d_in[13];
  float* out = (float*)d_out;

  char* ws = (char*)d_ws;
  unsigned short* A1 = (unsigned short*)ws;                       // 128 MiB
  float* part = (float*)(ws + ((size_t)64 << 20));                // A1 upper half (dead after gemm2)
  unsigned short* region = (unsigned short*)(ws + ((size_t)128 << 20));
  unsigned short* embb = region;                                  // phase 1
  unsigned short* FF = region;                                    // phase 2
  unsigned short* w1t = (unsigned short*)(ws + ((size_t)192 << 20));
  unsigned short* w2t = (unsigned short*)(ws + ((size_t)193 << 20));
  char* sb = ws + ((size_t)192 << 20);
  float* gate = (float*)sb;                                       // 256 KiB
  int* topidx = (int*)(sb + 262144);                              // 16 KiB
  float* hlast = (float*)(sb + 262144 + 16384);                   // 32 KiB
  float* ctxbuf = (float*)(sb + 262144 + 16384 + 32768);          // 32 KiB
  float* qpart = (float*)(sb + 262144 + 16384 + 65536);           // 256 KiB
  unsigned short* H = A1;                                         // A1 dead after gemm2

  hipFuncSetAttribute(reinterpret_cast<const void*>(gemm256_kernel<512, 1024, 4, true, true>),
                      hipFuncAttributeMaxDynamicSharedMemorySize, 65536);
  hipFuncSetAttribute(reinterpret_cast<const void*>(gemm256_kernel<1024, 512, 2, false, false>),
                      hipFuncAttributeMaxDynamicSharedMemorySize, 65536);

  cvtwt_kernel<<<12096, 256, 0, stream>>>(emb, embb, w1, w2, w1t, w2t);
  gemm256_kernel<512, 1024, 4, true, true>
      <<<1024, 512, 65536, stream>>>(seq, embb, w1t, b1, A1);
  gemm256_kernel<1024, 512, 2, false, false>
      <<<512, 512, 65536, stream>>>(nullptr, A1, w2t, b2, FF);
  ln_gate_kernel<<<16384, 256, 0, stream>>>(seq, emb, FF, H, ln_g, ln_b, wg, bg, gate, hlast);
  topk_kernel<<<16, 256, 0, stream>>>(gate, topidx);
  qpart_kernel<<<128, 256, 0, stream>>>(hlast, wq, bq, qpart);
  attn_kernel<<<64, 256, 0, stream>>>(H, qpart, topidx, ctxbuf);
  out_part_kernel<<<2000, 256, 0, stream>>>(ctxbuf, wo, part);
  out_reduce_kernel<<<2000, 256, 0, stream>>>(part, bo, out);
}

// Round 9
// 332.228 us; speedup vs baseline: 1.0414x; 1.0414x over previous
//
#include <hip/hip_runtime.h>

typedef __bf16 bf16x8 __attribute__((ext_vector_type(8)));
typedef float f32x4 __attribute__((ext_vector_type(4)));
typedef unsigned short ushort8v __attribute__((ext_vector_type(8)));

#define NB 16
#define NT 4096
#define NV 32000
#define ND 512
#define NH 1024
#define NSLOTS 256

__device__ __forceinline__ float b2f(unsigned short u) {
  unsigned int x = ((unsigned int)u) << 16;
  return __builtin_bit_cast(float, x);
}
__device__ __forceinline__ unsigned short f2b(float f) {
  unsigned int x = __builtin_bit_cast(unsigned int, f);
  unsigned int r = (x + 0x7FFFu + ((x >> 16) & 1u)) >> 16;
  return (unsigned short)r;
}

#define GLOAD_LDS16(g, l)                                                              \
  __builtin_amdgcn_global_load_lds((const __attribute__((address_space(1))) void*)(g), \
                                   (__attribute__((address_space(3))) void*)(l), 16, 0, 0)
#define BARRIER() asm volatile("s_barrier" ::: "memory")
#define VMCNT(n) asm volatile("s_waitcnt vmcnt(" #n ")" ::: "memory")

// ---------------------------------------------------------------------------
// Fused elementwise prep: emb f32->bf16 (blocks <8000) and w1/w2 transpose+cvt.
// ---------------------------------------------------------------------------
__global__ __launch_bounds__(256) void cvtwt_kernel(
    const float* __restrict__ emb, unsigned short* __restrict__ embb,
    const float* __restrict__ w1, const float* __restrict__ w2,
    unsigned short* __restrict__ w1t, unsigned short* __restrict__ w2t) {
  const int blk = blockIdx.x;
  if (blk < 8000) {
    const long base = ((long)blk * 256 + threadIdx.x) * 8;
    float4 a = *(const float4*)&emb[base];
    float4 b = *(const float4*)&emb[base + 4];
    ushort8v o;
    o[0] = f2b(a.x); o[1] = f2b(a.y); o[2] = f2b(a.z); o[3] = f2b(a.w);
    o[4] = f2b(b.x); o[5] = f2b(b.y); o[6] = f2b(b.z); o[7] = f2b(b.w);
    *(ushort8v*)&embb[base] = o;
  } else {
    const int i = (blk - 8000) * 256 + threadIdx.x;
    if (i < ND * NH) {
      const int n = i >> 9, k = i & 511;
      w1t[i] = f2b(w1[k * NH + n]);
    } else {
      const int j = i - ND * NH;
      const int n = j >> 10, k = j & 1023;
      w2t[j] = f2b(w2[k * ND + n]);
    }
  }
}

// ---------------------------------------------------------------------------
// 256x256 bf16 MFMA GEMM with 4-phase counted-vmcnt pipeline (T3+T4).
// BK=64, 8 waves (2M x 4N), per-wave 128x64 out. LDS 128 KiB = 2 bufs of
// (A 32KB | B 32KB), (row&7) XOR chunk swizzle (verified conflict-free r7).
// Phase j computes m in {2j,2j+1}; B-frags loaded once (phase 0), held in
// regs. Staging of tile t+1 spread 2 loads/phase in order B0,B1|B2,B3|A0,A2|
// A1,A3 so consumers are staged >=3 phases ahead. Counted waits (never 0 in
// steady state): vmcnt(4) end ph1 (retires this tile's A1,A3), vmcnt(2) end
// ph3 (retires next tile's B0-B3,A0,A2). Barrier between reads+stage and
// MFMA. Per-wave in-flight: 2 ->4 ->6(-2)->... steady, proven in journal.
// ---------------------------------------------------------------------------
template <int KDIM, int NLD, int NBN, bool GATHER, bool RELU>
__global__ __launch_bounds__(512, 2) void gemm256_kernel(
    const int* __restrict__ seq, const unsigned short* __restrict__ Abase,
    const unsigned short* __restrict__ Bt, const float* __restrict__ bias,
    unsigned short* __restrict__ Out) {
  extern __shared__ unsigned short smraw[];  // 2 x (A 16384 | B 16384) shorts
  const int tid = threadIdx.x;
  const int lane = tid & 63;
  const int w = tid >> 6;   // 0..7
  const int wm = w >> 2;    // 0..1
  const int wn = w & 3;     // 0..3

  const int id = blockIdx.x;
  const int swz = (id & 7) * (gridDim.x >> 3) + (id >> 3);
  const int bm = swz / NBN;
  const int bn = swz % NBN;

  // Staging: tile matrix = 256 rows x 8 chunks(16B). Inst k covers rows
  // k*64 + (tid>>3); LDS slot (row,c) holds global chunk c ^ (row&7).
  const int srow = tid >> 3;                       // 0..63
  const int schunk = (tid & 7) ^ (srow & 7);
  const unsigned short* aptr[4];
  const unsigned short* bptr[4];
#pragma unroll
  for (int k = 0; k < 4; ++k) {
    const int row = k * 64 + srow;
    long ar;
    if constexpr (GATHER)
      ar = seq[bm * 256 + row];
    else
      ar = bm * 256 + row;
    aptr[k] = Abase + (size_t)ar * KDIM + schunk * 8;
    bptr[k] = Bt + (size_t)(bn * 256 + row) * KDIM + schunk * 8;
  }

  const int fr = lane & 15;
  const int hi = lane >> 4;

  f32x4 acc[8][4] = {};
  bf16x8 bfr[4][2];  // B fragments, held across the tile's 4 phases

  auto stageA = [&](int buf, int k, int kt) {
    unsigned short* A = smraw + buf * 32768;
    GLOAD_LDS16(aptr[k] + kt * 64, &A[(k * 512 + w * 64) * 8]);
  };
  auto stageB = [&](int buf, int k, int kt) {
    unsigned short* B = smraw + buf * 32768 + 16384;
    GLOAD_LDS16(bptr[k] + kt * 64, &B[(k * 512 + w * 64) * 8]);
  };

  // Prologue: tile 0 into buf0, full drain.
#pragma unroll
  for (int k = 0; k < 4; ++k) stageB(0, k, 0);
#pragma unroll
  for (int k = 0; k < 4; ++k) stageA(0, k, 0);
  VMCNT(0);
  BARRIER();

#define LDFRAG(base, r, kk) \
  __builtin_bit_cast(bf16x8, *(const ushort8v*)&(base)[(r) * 64 + (((kk) * 4 + hi) ^ (fr & 7)) * 8])
#define MFMA_PHASE(j)                                                                   \
  __builtin_amdgcn_s_setprio(1);                                                        \
  _Pragma("unroll") for (int mm = 0; mm < 2; ++mm)                                      \
      _Pragma("unroll") for (int n = 0; n < 4; ++n)                                     \
          _Pragma("unroll") for (int kk = 0; kk < 2; ++kk)                              \
              acc[2 * (j) + mm][n] =                                                    \
                  __builtin_amdgcn_mfma_f32_16x16x32_bf16(af[mm][kk], bfr[n][kk],       \
                                                          acc[2 * (j) + mm][n], 0, 0, 0); \
  __builtin_amdgcn_s_setprio(0)

  constexpr int NKT = KDIM / 64;
  for (int t = 0; t < NKT; ++t) {
    const int cur = t & 1;
    const unsigned short* A = smraw + cur * 32768;
    const unsigned short* B = A + 16384;
    const bool hn = (t + 1 < NKT);
    const int nk = t + 1;
    bf16x8 af[2][2];
    // ---- phase 0: bf(all)+af(m0,m1); stage B0,B1
#pragma unroll
    for (int n = 0; n < 4; ++n)
#pragma unroll
      for (int kk = 0; kk < 2; ++kk) bfr[n][kk] = LDFRAG(B, wn * 64 + n * 16 + fr, kk);
#pragma unroll
    for (int mm = 0; mm < 2; ++mm)
#pragma unroll
      for (int kk = 0; kk < 2; ++kk) af[mm][kk] = LDFRAG(A, wm * 128 + mm * 16 + fr, kk);
    if (hn) { stageB(cur ^ 1, 0, nk); stageB(cur ^ 1, 1, nk); }
    BARRIER();
    MFMA_PHASE(0);
    // ---- phase 1: af(m2,m3); stage B2,B3; vmcnt retires this tile's A1,A3
#pragma unroll
    for (int mm = 0; mm < 2; ++mm)
#pragma unroll
      for (int kk = 0; kk < 2; ++kk)
        af[mm][kk] = LDFRAG(A, wm * 128 + (2 + mm) * 16 + fr, kk);
    if (hn) {
      stageB(cur ^ 1, 2, nk); stageB(cur ^ 1, 3, nk);
      VMCNT(4);
    } else {
      VMCNT(0);
    }
    BARRIER();
    MFMA_PHASE(1);
    // ---- phase 2: af(m4,m5); stage A0,A2
#pragma unroll
    for (int mm = 0; mm < 2; ++mm)
#pragma unroll
      for (int kk = 0; kk < 2; ++kk)
        af[mm][kk] = LDFRAG(A, wm * 128 + (4 + mm) * 16 + fr, kk);
    if (hn) { stageA(cur ^ 1, 0, nk); stageA(cur ^ 1, 2, nk); }
    BARRIER();
    MFMA_PHASE(2);
    // ---- phase 3: af(m6,m7); stage A1,A3; vmcnt(2) leaves only A1,A3 in flight
#pragma unroll
    for (int mm = 0; mm < 2; ++mm)
#pragma unroll
      for (int kk = 0; kk < 2; ++kk)
        af[mm][kk] = LDFRAG(A, wm * 128 + (6 + mm) * 16 + fr, kk);
    if (hn) {
      stageA(cur ^ 1, 1, nk); stageA(cur ^ 1, 3, nk);
      VMCNT(2);
    }
    BARRIER();
    MFMA_PHASE(3);
  }
  __syncthreads();  // all reads done before C repack reuses LDS

  // Epilogue: bias (+relu); repack through LDS [128][264] in two row-halves.
  float bb[4];
#pragma unroll
  for (int n = 0; n < 4; ++n) bb[n] = bias[bn * 256 + wn * 64 + n * 16 + fr];
  unsigned short* C = smraw;
#pragma unroll
  for (int h = 0; h < 2; ++h) {
    if (h) __syncthreads();
    if (wm == h) {
#pragma unroll
      for (int m = 0; m < 8; ++m)
#pragma unroll
        for (int n = 0; n < 4; ++n)
#pragma unroll
          for (int i = 0; i < 4; ++i) {
            float v = acc[m][n][i] + bb[n];
            if constexpr (RELU) v = fmaxf(v, 0.f);
            C[(m * 16 + hi * 4 + i) * 264 + wn * 64 + n * 16 + fr] = f2b(v);
          }
    }
    __syncthreads();
#pragma unroll
    for (int it = 0; it < 8; ++it) {
      const int idx = it * 512 + tid;
      const int lrow = idx >> 5;
      const int pos = idx & 31;
      ushort8v v = *(const ushort8v*)&C[lrow * 264 + pos * 8];
      *(ushort8v*)&Out[(size_t)(bm * 256 + h * 128 + lrow) * (size_t)NLD + bn * 256 + pos * 8] = v;
    }
  }
#undef LDFRAG
#undef MFMA_PHASE
}

// ---------------------------------------------------------------------------
// Fused residual + LayerNorm + gate (f32 math).
// ---------------------------------------------------------------------------
__global__ __launch_bounds__(256) void ln_gate_kernel(
    const int* __restrict__ seq, const float* __restrict__ emb,
    const unsigned short* __restrict__ FF, unsigned short* __restrict__ H,
    const float* __restrict__ ln_g, const float* __restrict__ ln_b,
    const float* __restrict__ wg, const float* __restrict__ bgp,
    float* __restrict__ gate, float* __restrict__ hlast) {
  const int lane = threadIdx.x & 63;
  const int w = threadIdx.x >> 6;
  const int t = blockIdx.x * 4 + w;
  const float* er = emb + (size_t)seq[t] * ND + lane * 8;
  ushort8v fv = *(const ushort8v*)&FF[(size_t)t * ND + lane * 8];
  float4 e0 = *(const float4*)er, e1 = *(const float4*)(er + 4);
  float x[8] = {b2f(fv[0]) + e0.x, b2f(fv[1]) + e0.y, b2f(fv[2]) + e0.z, b2f(fv[3]) + e0.w,
                b2f(fv[4]) + e1.x, b2f(fv[5]) + e1.y, b2f(fv[6]) + e1.z, b2f(fv[7]) + e1.w};
  float s = 0.f, sq = 0.f;
#pragma unroll
  for (int j = 0; j < 8; ++j) {
    s += x[j];
    sq += x[j] * x[j];
  }
#pragma unroll
  for (int o = 32; o; o >>= 1) {
    s += __shfl_xor(s, o);
    sq += __shfl_xor(sq, o);
  }
  const float mu = s * (1.f / 512.f);
  const float var = sq * (1.f / 512.f) - mu * mu;
  const float rs = rsqrtf(var + 1e-5f);
  float gd = 0.f;
  float h[8];
  ushort8v hv;
#pragma unroll
  for (int j = 0; j < 8; ++j) {
    const int col = lane * 8 + j;
    h[j] = (x[j] - mu) * rs * ln_g[col] + ln_b[col];
    hv[j] = f2b(h[j]);
    gd += h[j] * wg[col];
  }
  *(ushort8v*)&H[(size_t)t * ND + lane * 8] = hv;
#pragma unroll
  for (int o = 32; o; o >>= 1) gd += __shfl_xor(gd, o);
  if (lane == 0) gate[t] = 1.f / (1.f + expf(-(gd + bgp[0])));
  if ((t & (NT - 1)) == NT - 1) {
    const int b = t >> 12;
    float* hl = hlast + b * ND + lane * 8;
#pragma unroll
    for (int j = 0; j < 8; ++j) hl[j] = h[j];
  }
}

// ---------------------------------------------------------------------------
// Top-256 of 4096 per batch: radix threshold search on positive f32 bits.
// ---------------------------------------------------------------------------
__global__ __launch_bounds__(256) void topk_kernel(const float* __restrict__ gate,
                                                   int* __restrict__ topidx) {
  __shared__ unsigned int keys[NT];
  __shared__ int cnt;
  __shared__ int scan[256];
  const int b = blockIdx.x, tid = threadIdx.x;
  const float* g = gate + (size_t)b * NT;
  for (int i = tid; i < NT; i += 256) keys[i] = __builtin_bit_cast(unsigned int, g[i]);
  __syncthreads();
  unsigned int K = 0u;
  for (int bit = 31; bit >= 0; --bit) {
    const unsigned int cand = K | (1u << bit);
    if (tid == 0) cnt = 0;
    __syncthreads();
    int c = 0;
    for (int i = tid * 16; i < tid * 16 + 16; ++i) c += (keys[i] >= cand) ? 1 : 0;
    if (c) atomicAdd(&cnt, c);
    __syncthreads();
    const int cn = cnt;
    __syncthreads();
    if (cn >= NSLOTS) K = cand;
  }
  int gcnt = 0, ecnt = 0;
  for (int i = tid * 16; i < tid * 16 + 16; ++i) {
    gcnt += (keys[i] > K) ? 1 : 0;
    ecnt += (keys[i] == K) ? 1 : 0;
  }
  scan[tid] = gcnt;
  __syncthreads();
  for (int off = 1; off < 256; off <<= 1) {
    int v2 = (tid >= off) ? scan[tid - off] : 0;
    __syncthreads();
    scan[tid] += v2;
    __syncthreads();
  }
  const int gi = scan[tid];
  const int tot_gt = scan[255];
  __syncthreads();
  scan[tid] = ecnt;
  __syncthreads();
  for (int off = 1; off < 256; off <<= 1) {
    int v2 = (tid >= off) ? scan[tid - off] : 0;
    __syncthreads();
    scan[tid] += v2;
    __syncthreads();
  }
  const int ei = scan[tid];
  int gpos = gi - gcnt;
  int epos = tot_gt + (ei - ecnt);
  int* outp = topidx + b * NSLOTS;
  for (int i = tid * 16; i < tid * 16 + 16; ++i) {
    if (keys[i] > K) {
      outp[gpos++] = i;
    } else if (keys[i] == K) {
      if (epos < NSLOTS) outp[epos] = i;
      epos++;
    }
  }
}

// ---------------------------------------------------------------------------
// qpart[b][s][c] = sum_{d in slice s} hlast[b][d]*wq[d][c]  (+bq when s==0)
// ---------------------------------------------------------------------------
__global__ __launch_bounds__(256) void qpart_kernel(const float* __restrict__ hlast,
                                                    const float* __restrict__ wq,
                                                    const float* __restrict__ bq,
                                                    float* __restrict__ qpart) {
  const int blk = blockIdx.x;
  const int b = blk >> 3, s = blk & 7;
  const int c0 = threadIdx.x;
  const int d0 = s * 64;
  float a0 = 0.f, a1 = 0.f;
#pragma unroll 4
  for (int dd = 0; dd < 64; ++dd) {
    const float hv = hlast[b * ND + d0 + dd];
    a0 += hv * wq[(size_t)(d0 + dd) * ND + c0];
    a1 += hv * wq[(size_t)(d0 + dd) * ND + c0 + 256];
  }
  if (s == 0) {
    a0 += bq[c0];
    a1 += bq[c0 + 256];
  }
  float* qp = qpart + ((size_t)b * 8 + s) * ND;
  qp[c0] = a0;
  qp[c0 + 256] = a1;
}

// ---------------------------------------------------------------------------
// Fused scores + softmax + ctx. 64 blocks = 16 batches x 4 d-chunks of 128.
// ---------------------------------------------------------------------------
__global__ __launch_bounds__(256) void attn_kernel(
    const unsigned short* __restrict__ H, const float* __restrict__ qpart,
    const int* __restrict__ topidx, float* __restrict__ ctx) {
  __shared__ float qs[512];
  __shared__ float attnv[256];
  __shared__ int idxs[256];
  __shared__ float red[4];
  __shared__ float part[2][128];
  const int blk = blockIdx.x;
  const int b = blk >> 2, dc = blk & 3;
  const int tid = threadIdx.x;
  const int lane = tid & 63, wv = tid >> 6;
  {
    float a0 = 0.f, a1 = 0.f;
#pragma unroll
    for (int s = 0; s < 8; ++s) {
      const float* qp = qpart + ((size_t)b * 8 + s) * ND;
      a0 += qp[tid];
      a1 += qp[tid + 256];
    }
    qs[tid] = a0;
    qs[tid + 256] = a1;
  }
  idxs[tid] = topidx[b * 256 + tid];
  __syncthreads();
  const unsigned short* hr = H + ((size_t)b * NT + idxs[tid]) * ND;
  float sc = 0.f;
  for (int d0 = 0; d0 < 512; d0 += 8) {
    ushort8v hv = *(const ushort8v*)&hr[d0];
#pragma unroll
    for (int j = 0; j < 8; ++j) sc += b2f(hv[j]) * qs[d0 + j];
  }
  float m = sc;
#pragma unroll
  for (int o = 32; o; o >>= 1) m = fmaxf(m, __shfl_xor(m, o));
  if (lane == 0) red[wv] = m;
  __syncthreads();
  m = fmaxf(fmaxf(red[0], red[1]), fmaxf(red[2], red[3]));
  __syncthreads();
  const float e = expf(sc - m);
  float ssum = e;
#pragma unroll
  for (int o = 32; o; o >>= 1) ssum += __shfl_xor(ssum, o);
  if (lane == 0) red[wv] = ssum;
  __syncthreads();
  ssum = red[0] + red[1] + red[2] + red[3];
  attnv[tid] = e / ssum;
  __syncthreads();
  const int d = dc * 128 + (tid & 127);
  const int kh = tid >> 7;
  float c = 0.f;
#pragma unroll 4
  for (int k2 = 0; k2 < 128; ++k2) {
    const int k = kh * 128 + k2;
    c += attnv[k] * b2f(H[((size_t)b * NT + idxs[k]) * ND + d]);
  }
  part[kh][tid & 127] = c;
  __syncthreads();
  if (tid < 128) ctx[b * 512 + dc * 128 + tid] = part[0][tid] + part[1][tid];
}

// ---------------------------------------------------------------------------
// Out-projection stage 1: part[s][b][v] = sum_{d in slice s(32)} ctx[b][d]*wo[d][v]
// ---------------------------------------------------------------------------
__global__ __launch_bounds__(256) void out_part_kernel(const float* __restrict__ ctx,
                                                       const float* __restrict__ wo,
                                                       float* __restrict__ part) {
  const int blk = blockIdx.x;
  const int ct = blk % 125, s = blk / 125;
  const int v = ct * 256 + threadIdx.x;
  const int d0 = s * 32;
  const float* wp = wo + (size_t)d0 * NV + v;
  float acc[16] = {};
#pragma unroll 4
  for (int dd = 0; dd < 32; ++dd) {
    const float wv = wp[(size_t)dd * NV];
#pragma unroll
    for (int bb = 0; bb < 16; ++bb) acc[bb] += ctx[bb * ND + d0 + dd] * wv;
  }
  float* pp = part + (size_t)s * NB * NV + v;
#pragma unroll
  for (int bb = 0; bb < 16; ++bb) pp[(size_t)bb * NV] = acc[bb];
}

// ---------------------------------------------------------------------------
// Out-projection stage 2: out[b][v] = sum_s part[s][b][v] + bo[v]
// ---------------------------------------------------------------------------
__global__ __launch_bounds__(256) void out_reduce_kernel(const float* __restrict__ part,
                                                         const float* __restrict__ bo,
                                                         float* __restrict__ out) {
  const int i = blockIdx.x * 256 + threadIdx.x;
  const int b = i / NV;
  const int v = i - b * NV;
  float a = bo[v];
#pragma unroll
  for (int s = 0; s < 16; ++s) a += part[(size_t)s * NB * NV + i];
  out[i] = a;
}

// ---------------------------------------------------------------------------
// Workspace layout (total 194.0 MiB):
//   A1     @ 0        : 128 MiB (gemm1 out). After gemm2: 0..64Mi = H,
//                       64Mi..96.8Mi = out-projection partials.
//   region @ 128 MiB  : 64 MiB — embb (phase 1), then FF bf16 (phase 2)
//   w1t    @ 192 MiB  : 1 MiB — dead after gemm1; aliased by small buffers
//   w2t    @ 193 MiB  : 1 MiB
// ---------------------------------------------------------------------------
extern "C" void kernel_launch(void* const* d_in, const int* in_sizes, int n_in,
                              void* d_out, int out_size, void* d_ws, size_t ws_size,
                              hipStream_t stream) {
  const int* seq = (const int*)d_in[0];
  const float* emb = (const float*)d_in[1];
  const float* w1 = (const float*)d_in[2];
  const float* b1 = (const float*)d_in[3];
  const float* w2 = (const float*)d_in[4];
  const float* b2 = (const float*)d_in[5];
  const float* ln_g = (const float*)d_in[6];
  const float* ln_b = (const float*)d_in[7];
  const float* wg = (const float*)d_in[8];
  const float* bg = (const float*)d_in[9];
  const float* wq = (const float*)d_in[10];
  const float* bq = (const float*)d_in[11];
  const float* wo = (const float*)d_in[12];
  const float* bo = (const float*)d_in[13];
  float* out = (float*)d_out;

  char* ws = (char*)d_ws;
  unsigned short* A1 = (unsigned short*)ws;                       // 128 MiB
  float* part = (float*)(ws + ((size_t)64 << 20));                // A1 upper half (dead after gemm2)
  unsigned short* region = (unsigned short*)(ws + ((size_t)128 << 20));
  unsigned short* embb = region;                                  // phase 1
  unsigned short* FF = region;                                    // phase 2
  unsigned short* w1t = (unsigned short*)(ws + ((size_t)192 << 20));
  unsigned short* w2t = (unsigned short*)(ws + ((size_t)193 << 20));
  char* sb = ws + ((size_t)192 << 20);
  float* gate = (float*)sb;                                       // 256 KiB
  int* topidx = (int*)(sb + 262144);                              // 16 KiB
  float* hlast = (float*)(sb + 262144 + 16384);                   // 32 KiB
  float* ctxbuf = (float*)(sb + 262144 + 16384 + 32768);          // 32 KiB
  float* qpart = (float*)(sb + 262144 + 16384 + 65536);           // 256 KiB
  unsigned short* H = A1;                                         // A1 dead after gemm2

  hipFuncSetAttribute(reinterpret_cast<const void*>(gemm256_kernel<512, 1024, 4, true, true>),
                      hipFuncAttributeMaxDynamicSharedMemorySize, 131072);
  hipFuncSetAttribute(reinterpret_cast<const void*>(gemm256_kernel<1024, 512, 2, false, false>),
                      hipFuncAttributeMaxDynamicSharedMemorySize, 131072);

  cvtwt_kernel<<<12096, 256, 0, stream>>>(emb, embb, w1, w2, w1t, w2t);
  gemm256_kernel<512, 1024, 4, true, true>
      <<<1024, 512, 131072, stream>>>(seq, embb, w1t, b1, A1);
  gemm256_kernel<1024, 512, 2, false, false>
      <<<512, 512, 131072, stream>>>(nullptr, A1, w2t, b2, FF);
  ln_gate_kernel<<<16384, 256, 0, stream>>>(seq, emb, FF, H, ln_g, ln_b, wg, bg, gate, hlast);
  topk_kernel<<<16, 256, 0, stream>>>(gate, topidx);
  qpart_kernel<<<128, 256, 0, stream>>>(hlast, wq, bq, qpart);
  attn_kernel<<<64, 256, 0, stream>>>(H, qpart, topidx, ctxbuf);
  out_part_kernel<<<2000, 256, 0, stream>>>(ctxbuf, wo, part);
  out_reduce_kernel<<<2000, 256, 0, stream>>>(part, bo, out);
}

// Round 10
// 330.699 us; speedup vs baseline: 1.0462x; 1.0046x over previous
//
#include <hip/hip_runtime.h>

typedef __bf16 bf16x8 __attribute__((ext_vector_type(8)));
typedef float f32x4 __attribute__((ext_vector_type(4)));
typedef unsigned short ushort8v __attribute__((ext_vector_type(8)));

#define NB 16
#define NT 4096
#define NV 32000
#define ND 512
#define NH 1024
#define NSLOTS 256

__device__ __forceinline__ float b2f(unsigned short u) {
  unsigned int x = ((unsigned int)u) << 16;
  return __builtin_bit_cast(float, x);
}
__device__ __forceinline__ unsigned short f2b(float f) {
  unsigned int x = __builtin_bit_cast(unsigned int, f);
  unsigned int r = (x + 0x7FFFu + ((x >> 16) & 1u)) >> 16;
  return (unsigned short)r;
}

#define GLOAD_LDS16(g, l)                                                              \
  __builtin_amdgcn_global_load_lds((const __attribute__((address_space(1))) void*)(g), \
                                   (__attribute__((address_space(3))) void*)(l), 16, 0, 0)
#define BARRIER() asm volatile("s_barrier" ::: "memory")
#define VMCNT(n) asm volatile("s_waitcnt vmcnt(" #n ")" ::: "memory")
// rule #18: inline lgkmcnt(0) must be followed by sched_barrier(0) or hipcc
// hoists register-only MFMA past the wait.
#define LGKM0()                                               \
  do {                                                        \
    asm volatile("s_waitcnt lgkmcnt(0)" ::: "memory");        \
    __builtin_amdgcn_sched_barrier(0);                        \
  } while (0)

// ---------------------------------------------------------------------------
// Fused elementwise prep: emb f32->bf16 (blocks <8000) and w1/w2 transpose+cvt.
// ---------------------------------------------------------------------------
__global__ __launch_bounds__(256) void cvtwt_kernel(
    const float* __restrict__ emb, unsigned short* __restrict__ embb,
    const float* __restrict__ w1, const float* __restrict__ w2,
    unsigned short* __restrict__ w1t, unsigned short* __restrict__ w2t) {
  const int blk = blockIdx.x;
  if (blk < 8000) {
    const long base = ((long)blk * 256 + threadIdx.x) * 8;
    float4 a = *(const float4*)&emb[base];
    float4 b = *(const float4*)&emb[base + 4];
    ushort8v o;
    o[0] = f2b(a.x); o[1] = f2b(a.y); o[2] = f2b(a.z); o[3] = f2b(a.w);
    o[4] = f2b(b.x); o[5] = f2b(b.y); o[6] = f2b(b.z); o[7] = f2b(b.w);
    *(ushort8v*)&embb[base] = o;
  } else {
    const int i = (blk - 8000) * 256 + threadIdx.x;
    if (i < ND * NH) {
      const int n = i >> 9, k = i & 511;
      w1t[i] = f2b(w1[k * NH + n]);
    } else {
      const int j = i - ND * NH;
      const int n = j >> 10, k = j & 1023;
      w2t[j] = f2b(w2[k * ND + n]);
    }
  }
}

// ---------------------------------------------------------------------------
// 256x256 bf16 MFMA GEMM, m201-style 4-phase schedule per K-tile (BK=64):
// per phase: {ds_read subtile + stage 2 gload_lds} -> s_barrier -> lgkmcnt(0)
// + sched_barrier(0) -> pure-MFMA cluster (setprio-wrapped) -> s_barrier.
// Counted vmcnt (never 0 in steady state): vmcnt(4) at P1 retires this
// tile's A1,A3 before P2 reads those rows; vmcnt(2) at P3 retires next
// tile's B0-B3,A0,A2, leaving A1,A3 in flight across the tile boundary.
// 8 waves (2M x 4N), per-wave 128x64 out, 128 KiB LDS 2-buf, (row&7) XOR
// chunk swizzle (conflict-free, verified r7/r9), XCD block swizzle.
// ---------------------------------------------------------------------------
template <int KDIM, int NLD, int NBN, bool GATHER, bool RELU>
__global__ __launch_bounds__(512, 2) void gemm256_kernel(
    const int* __restrict__ seq, const unsigned short* __restrict__ Abase,
    const unsigned short* __restrict__ Bt, const float* __restrict__ bias,
    unsigned short* __restrict__ Out) {
  extern __shared__ unsigned short smraw[];  // 2 x (A 16384 | B 16384) shorts
  const int tid = threadIdx.x;
  const int lane = tid & 63;
  const int w = tid >> 6;   // 0..7
  const int wm = w >> 2;    // 0..1
  const int wn = w & 3;     // 0..3

  const int id = blockIdx.x;
  const int swz = (id & 7) * (gridDim.x >> 3) + (id >> 3);
  const int bm = swz / NBN;
  const int bn = swz % NBN;

  // Staging: tile matrix = 256 rows x 8 chunks(16B). Inst k covers rows
  // k*64 + (tid>>3); LDS slot (row,c) holds global chunk c ^ (row&7).
  const int srow = tid >> 3;                       // 0..63
  const int schunk = (tid & 7) ^ (srow & 7);
  const unsigned short* aptr[4];
  const unsigned short* bptr[4];
#pragma unroll
  for (int k = 0; k < 4; ++k) {
    const int row = k * 64 + srow;
    long ar;
    if constexpr (GATHER)
      ar = seq[bm * 256 + row];
    else
      ar = bm * 256 + row;
    aptr[k] = Abase + (size_t)ar * KDIM + schunk * 8;
    bptr[k] = Bt + (size_t)(bn * 256 + row) * KDIM + schunk * 8;
  }

  const int fr = lane & 15;
  const int hi = lane >> 4;

  f32x4 acc[8][4] = {};
  bf16x8 bfr[4][2];  // B fragments, held across the tile's 4 phases

  auto stageA = [&](int buf, int k, int kt) {
    unsigned short* A = smraw + buf * 32768;
    GLOAD_LDS16(aptr[k] + kt * 64, &A[(k * 512 + w * 64) * 8]);
  };
  auto stageB = [&](int buf, int k, int kt) {
    unsigned short* B = smraw + buf * 32768 + 16384;
    GLOAD_LDS16(bptr[k] + kt * 64, &B[(k * 512 + w * 64) * 8]);
  };

  // Prologue: tile 0 into buf0, full drain.
#pragma unroll
  for (int k = 0; k < 4; ++k) stageB(0, k, 0);
#pragma unroll
  for (int k = 0; k < 4; ++k) stageA(0, k, 0);
  VMCNT(0);
  BARRIER();

#define LDFRAG(base, r, kk) \
  __builtin_bit_cast(bf16x8, *(const ushort8v*)&(base)[(r) * 64 + (((kk) * 4 + hi) ^ (fr & 7)) * 8])
#define MFMA_PHASE(j)                                                                   \
  __builtin_amdgcn_s_setprio(1);                                                        \
  _Pragma("unroll") for (int mm = 0; mm < 2; ++mm)                                      \
      _Pragma("unroll") for (int n = 0; n < 4; ++n)                                     \
          _Pragma("unroll") for (int kk = 0; kk < 2; ++kk)                              \
              acc[2 * (j) + mm][n] =                                                    \
                  __builtin_amdgcn_mfma_f32_16x16x32_bf16(af[mm][kk], bfr[n][kk],       \
                                                          acc[2 * (j) + mm][n], 0, 0, 0); \
  __builtin_amdgcn_s_setprio(0)

  constexpr int NKT = KDIM / 64;
  for (int t = 0; t < NKT; ++t) {
    const int cur = t & 1;
    const unsigned short* A = smraw + cur * 32768;
    const unsigned short* B = A + 16384;
    const bool hn = (t + 1 < NKT);
    const int nk = t + 1;
    bf16x8 af[2][2];
    // ---- phase 0: read bf(all)+af(m0,m1); stage B0,B1
#pragma unroll
    for (int n = 0; n < 4; ++n)
#pragma unroll
      for (int kk = 0; kk < 2; ++kk) bfr[n][kk] = LDFRAG(B, wn * 64 + n * 16 + fr, kk);
#pragma unroll
    for (int mm = 0; mm < 2; ++mm)
#pragma unroll
      for (int kk = 0; kk < 2; ++kk) af[mm][kk] = LDFRAG(A, wm * 128 + mm * 16 + fr, kk);
    if (hn) { stageB(cur ^ 1, 0, nk); stageB(cur ^ 1, 1, nk); }
    BARRIER();
    LGKM0();
    MFMA_PHASE(0);
    BARRIER();
    // ---- phase 1: read af(m2,m3); stage B2,B3; vmcnt(4) retires A1,A3 of this tile
#pragma unroll
    for (int mm = 0; mm < 2; ++mm)
#pragma unroll
      for (int kk = 0; kk < 2; ++kk)
        af[mm][kk] = LDFRAG(A, wm * 128 + (2 + mm) * 16 + fr, kk);
    if (hn) {
      stageB(cur ^ 1, 2, nk); stageB(cur ^ 1, 3, nk);
      VMCNT(4);
    } else {
      VMCNT(0);
    }
    BARRIER();
    LGKM0();
    MFMA_PHASE(1);
    BARRIER();
    // ---- phase 2: read af(m4,m5); stage A0,A2
#pragma unroll
    for (int mm = 0; mm < 2; ++mm)
#pragma unroll
      for (int kk = 0; kk < 2; ++kk)
        af[mm][kk] = LDFRAG(A, wm * 128 + (4 + mm) * 16 + fr, kk);
    if (hn) { stageA(cur ^ 1, 0, nk); stageA(cur ^ 1, 2, nk); }
    BARRIER();
    LGKM0();
    MFMA_PHASE(2);
    BARRIER();
    // ---- phase 3: read af(m6,m7); stage A1,A3; vmcnt(2) leaves A1,A3 in flight
#pragma unroll
    for (int mm = 0; mm < 2; ++mm)
#pragma unroll
      for (int kk = 0; kk < 2; ++kk)
        af[mm][kk] = LDFRAG(A, wm * 128 + (6 + mm) * 16 + fr, kk);
    if (hn) {
      stageA(cur ^ 1, 1, nk); stageA(cur ^ 1, 3, nk);
      VMCNT(2);
    }
    BARRIER();
    LGKM0();
    MFMA_PHASE(3);
    BARRIER();
  }
  __syncthreads();  // all reads done before C repack reuses LDS

  // Epilogue: bias (+relu); repack through LDS [128][264] in two row-halves.
  float bb[4];
#pragma unroll
  for (int n = 0; n < 4; ++n) bb[n] = bias[bn * 256 + wn * 64 + n * 16 + fr];
  unsigned short* C = smraw;
#pragma unroll
  for (int h = 0; h < 2; ++h) {
    if (h) __syncthreads();
    if (wm == h) {
#pragma unroll
      for (int m = 0; m < 8; ++m)
#pragma unroll
        for (int n = 0; n < 4; ++n)
#pragma unroll
          for (int i = 0; i < 4; ++i) {
            float v = acc[m][n][i] + bb[n];
            if constexpr (RELU) v = fmaxf(v, 0.f);
            C[(m * 16 + hi * 4 + i) * 264 + wn * 64 + n * 16 + fr] = f2b(v);
          }
    }
    __syncthreads();
#pragma unroll
    for (int it = 0; it < 8; ++it) {
      const int idx = it * 512 + tid;
      const int lrow = idx >> 5;
      const int pos = idx & 31;
      ushort8v v = *(const ushort8v*)&C[lrow * 264 + pos * 8];
      *(ushort8v*)&Out[(size_t)(bm * 256 + h * 128 + lrow) * (size_t)NLD + bn * 256 + pos * 8] = v;
    }
  }
#undef LDFRAG
#undef MFMA_PHASE
}

// ---------------------------------------------------------------------------
// Fused residual + LayerNorm + gate (f32 math).
// ---------------------------------------------------------------------------
__global__ __launch_bounds__(256) void ln_gate_kernel(
    const int* __restrict__ seq, const float* __restrict__ emb,
    const unsigned short* __restrict__ FF, unsigned short* __restrict__ H,
    const float* __restrict__ ln_g, const float* __restrict__ ln_b,
    const float* __restrict__ wg, const float* __restrict__ bgp,
    float* __restrict__ gate, float* __restrict__ hlast) {
  const int lane = threadIdx.x & 63;
  const int w = threadIdx.x >> 6;
  const int t = blockIdx.x * 4 + w;
  const float* er = emb + (size_t)seq[t] * ND + lane * 8;
  ushort8v fv = *(const ushort8v*)&FF[(size_t)t * ND + lane * 8];
  float4 e0 = *(const float4*)er, e1 = *(const float4*)(er + 4);
  float x[8] = {b2f(fv[0]) + e0.x, b2f(fv[1]) + e0.y, b2f(fv[2]) + e0.z, b2f(fv[3]) + e0.w,
                b2f(fv[4]) + e1.x, b2f(fv[5]) + e1.y, b2f(fv[6]) + e1.z, b2f(fv[7]) + e1.w};
  float s = 0.f, sq = 0.f;
#pragma unroll
  for (int j = 0; j < 8; ++j) {
    s += x[j];
    sq += x[j] * x[j];
  }
#pragma unroll
  for (int o = 32; o; o >>= 1) {
    s += __shfl_xor(s, o);
    sq += __shfl_xor(sq, o);
  }
  const float mu = s * (1.f / 512.f);
  const float var = sq * (1.f / 512.f) - mu * mu;
  const float rs = rsqrtf(var + 1e-5f);
  float gd = 0.f;
  float h[8];
  ushort8v hv;
#pragma unroll
  for (int j = 0; j < 8; ++j) {
    const int col = lane * 8 + j;
    h[j] = (x[j] - mu) * rs * ln_g[col] + ln_b[col];
    hv[j] = f2b(h[j]);
    gd += h[j] * wg[col];
  }
  *(ushort8v*)&H[(size_t)t * ND + lane * 8] = hv;
#pragma unroll
  for (int o = 32; o; o >>= 1) gd += __shfl_xor(gd, o);
  if (lane == 0) gate[t] = 1.f / (1.f + expf(-(gd + bgp[0])));
  if ((t & (NT - 1)) == NT - 1) {
    const int b = t >> 12;
    float* hl = hlast + b * ND + lane * 8;
#pragma unroll
    for (int j = 0; j < 8; ++j) hl[j] = h[j];
  }
}

// ---------------------------------------------------------------------------
// Merged: blocks 0..15 = per-batch top-256 radix select; blocks 16..143 =
// qpart[b][s][c] = sum_{d in slice s} hlast[b][d]*wq[d][c] (+bq when s==0).
// ---------------------------------------------------------------------------
__global__ __launch_bounds__(256) void topk_qpart_kernel(
    const float* __restrict__ gate, int* __restrict__ topidx,
    const float* __restrict__ hlast, const float* __restrict__ wq,
    const float* __restrict__ bq, float* __restrict__ qpart) {
  __shared__ unsigned int keys[NT];
  __shared__ int cnt;
  __shared__ int scan[256];
  const int tid = threadIdx.x;
  if (blockIdx.x >= 16) {
    const int blk = blockIdx.x - 16;
    const int b = blk >> 3, s = blk & 7;
    const int d0 = s * 64;
    float a0 = 0.f, a1 = 0.f;
#pragma unroll 4
    for (int dd = 0; dd < 64; ++dd) {
      const float hv = hlast[b * ND + d0 + dd];
      a0 += hv * wq[(size_t)(d0 + dd) * ND + tid];
      a1 += hv * wq[(size_t)(d0 + dd) * ND + tid + 256];
    }
    if (s == 0) {
      a0 += bq[tid];
      a1 += bq[tid + 256];
    }
    float* qp = qpart + ((size_t)b * 8 + s) * ND;
    qp[tid] = a0;
    qp[tid + 256] = a1;
    return;
  }
  const int b = blockIdx.x;
  const float* g = gate + (size_t)b * NT;
  for (int i = tid; i < NT; i += 256) keys[i] = __builtin_bit_cast(unsigned int, g[i]);
  __syncthreads();
  unsigned int K = 0u;
  for (int bit = 31; bit >= 0; --bit) {
    const unsigned int cand = K | (1u << bit);
    if (tid == 0) cnt = 0;
    __syncthreads();
    int c = 0;
    for (int i = tid * 16; i < tid * 16 + 16; ++i) c += (keys[i] >= cand) ? 1 : 0;
    if (c) atomicAdd(&cnt, c);
    __syncthreads();
    const int cn = cnt;
    __syncthreads();
    if (cn >= NSLOTS) K = cand;
  }
  int gcnt = 0, ecnt = 0;
  for (int i = tid * 16; i < tid * 16 + 16; ++i) {
    gcnt += (keys[i] > K) ? 1 : 0;
    ecnt += (keys[i] == K) ? 1 : 0;
  }
  scan[tid] = gcnt;
  __syncthreads();
  for (int off = 1; off < 256; off <<= 1) {
    int v2 = (tid >= off) ? scan[tid - off] : 0;
    __syncthreads();
    scan[tid] += v2;
    __syncthreads();
  }
  const int gi = scan[tid];
  const int tot_gt = scan[255];
  __syncthreads();
  scan[tid] = ecnt;
  __syncthreads();
  for (int off = 1; off < 256; off <<= 1) {
    int v2 = (tid >= off) ? scan[tid - off] : 0;
    __syncthreads();
    scan[tid] += v2;
    __syncthreads();
  }
  const int ei = scan[tid];
  int gpos = gi - gcnt;
  int epos = tot_gt + (ei - ecnt);
  int* outp = topidx + b * NSLOTS;
  for (int i = tid * 16; i < tid * 16 + 16; ++i) {
    if (keys[i] > K) {
      outp[gpos++] = i;
    } else if (keys[i] == K) {
      if (epos < NSLOTS) outp[epos] = i;
      epos++;
    }
  }
}

// ---------------------------------------------------------------------------
// Fused scores + softmax + ctx. 64 blocks = 16 batches x 4 d-chunks of 128.
// ---------------------------------------------------------------------------
__global__ __launch_bounds__(256) void attn_kernel(
    const unsigned short* __restrict__ H, const float* __restrict__ qpart,
    const int* __restrict__ topidx, float* __restrict__ ctx) {
  __shared__ float qs[512];
  __shared__ float attnv[256];
  __shared__ int idxs[256];
  __shared__ float red[4];
  __shared__ float part[2][128];
  const int blk = blockIdx.x;
  const int b = blk >> 2, dc = blk & 3;
  const int tid = threadIdx.x;
  const int lane = tid & 63, wv = tid >> 6;
  {
    float a0 = 0.f, a1 = 0.f;
#pragma unroll
    for (int s = 0; s < 8; ++s) {
      const float* qp = qpart + ((size_t)b * 8 + s) * ND;
      a0 += qp[tid];
      a1 += qp[tid + 256];
    }
    qs[tid] = a0;
    qs[tid + 256] = a1;
  }
  idxs[tid] = topidx[b * 256 + tid];
  __syncthreads();
  const unsigned short* hr = H + ((size_t)b * NT + idxs[tid]) * ND;
  float sc = 0.f;
  for (int d0 = 0; d0 < 512; d0 += 8) {
    ushort8v hv = *(const ushort8v*)&hr[d0];
#pragma unroll
    for (int j = 0; j < 8; ++j) sc += b2f(hv[j]) * qs[d0 + j];
  }
  float m = sc;
#pragma unroll
  for (int o = 32; o; o >>= 1) m = fmaxf(m, __shfl_xor(m, o));
  if (lane == 0) red[wv] = m;
  __syncthreads();
  m = fmaxf(fmaxf(red[0], red[1]), fmaxf(red[2], red[3]));
  __syncthreads();
  const float e = expf(sc - m);
  float ssum = e;
#pragma unroll
  for (int o = 32; o; o >>= 1) ssum += __shfl_xor(ssum, o);
  if (lane == 0) red[wv] = ssum;
  __syncthreads();
  ssum = red[0] + red[1] + red[2] + red[3];
  attnv[tid] = e / ssum;
  __syncthreads();
  const int d = dc * 128 + (tid & 127);
  const int kh = tid >> 7;
  float c = 0.f;
#pragma unroll 4
  for (int k2 = 0; k2 < 128; ++k2) {
    const int k = kh * 128 + k2;
    c += attnv[k] * b2f(H[((size_t)b * NT + idxs[k]) * ND + d]);
  }
  part[kh][tid & 127] = c;
  __syncthreads();
  if (tid < 128) ctx[b * 512 + dc * 128 + tid] = part[0][tid] + part[1][tid];
}

// ---------------------------------------------------------------------------
// Out-projection stage 1: part[s][b][v] = sum_{d in slice s(64)} ctx[b][d]*wo[d][v]
// 1000 blocks = 125 col-tiles x 8 slices. ctx read scalar (uniform address).
// ---------------------------------------------------------------------------
__global__ __launch_bounds__(256) void out_part_kernel(const float* __restrict__ ctx,
                                                       const float* __restrict__ wo,
                                                       float* __restrict__ part) {
  const int blk = blockIdx.x;
  const int ct = blk % 125, s = blk / 125;
  const int v = ct * 256 + threadIdx.x;
  const int d0 = s * 64;
  const float* wp = wo + (size_t)d0 * NV + v;
  float acc[16] = {};
#pragma unroll 4
  for (int dd = 0; dd < 64; ++dd) {
    const float wv = wp[(size_t)dd * NV];
#pragma unroll
    for (int bb = 0; bb < 16; ++bb) acc[bb] += ctx[bb * ND + d0 + dd] * wv;
  }
  float* pp = part + (size_t)s * NB * NV + v;
#pragma unroll
  for (int bb = 0; bb < 16; ++bb) pp[(size_t)bb * NV] = acc[bb];
}

// ---------------------------------------------------------------------------
// Out-projection stage 2: out[b][v] = sum_s part[s][b][v] + bo[v]
// ---------------------------------------------------------------------------
__global__ __launch_bounds__(256) void out_reduce_kernel(const float* __restrict__ part,
                                                         const float* __restrict__ bo,
                                                         float* __restrict__ out) {
  const int i = blockIdx.x * 256 + threadIdx.x;
  const int b = i / NV;
  const int v = i - b * NV;
  float a = bo[v];
#pragma unroll
  for (int s = 0; s < 8; ++s) a += part[(size_t)s * NB * NV + i];
  out[i] = a;
}

// ---------------------------------------------------------------------------
// Workspace layout (total 194.0 MiB):
//   A1     @ 0        : 128 MiB (gemm1 out). After gemm2: 0..64Mi = H,
//                       64Mi..80.4Mi = out-projection partials (16.4 MB).
//   region @ 128 MiB  : 64 MiB — embb (phase 1), then FF bf16 (phase 2)
//   w1t    @ 192 MiB  : 1 MiB — dead after gemm1; aliased by small buffers
//   w2t    @ 193 MiB  : 1 MiB
// ---------------------------------------------------------------------------
extern "C" void kernel_launch(void* const* d_in, const int* in_sizes, int n_in,
                              void* d_out, int out_size, void* d_ws, size_t ws_size,
                              hipStream_t stream) {
  const int* seq = (const int*)d_in[0];
  const float* emb = (const float*)d_in[1];
  const float* w1 = (const float*)d_in[2];
  const float* b1 = (const float*)d_in[3];
  const float* w2 = (const float*)d_in[4];
  const float* b2 = (const float*)d_in[5];
  const float* ln_g = (const float*)d_in[6];
  const float* ln_b = (const float*)d_in[7];
  const float* wg = (const float*)d_in[8];
  const float* bg = (const float*)d_in[9];
  const float* wq = (const float*)d_in[10];
  const float* bq = (const float*)d_in[11];
  const float* wo = (const float*)d_in[12];
  const float* bo = (const float*)d_in[13];
  float* out = (float*)d_out;

  char* ws = (char*)d_ws;
  unsigned short* A1 = (unsigned short*)ws;                       // 128 MiB
  float* part = (float*)(ws + ((size_t)64 << 20));                // A1 upper half (dead after gemm2)
  unsigned short* region = (unsigned short*)(ws + ((size_t)128 << 20));
  unsigned short* embb = region;                                  // phase 1
  unsigned short* FF = region;                                    // phase 2
  unsigned short* w1t = (unsigned short*)(ws + ((size_t)192 << 20));
  unsigned short* w2t = (unsigned short*)(ws + ((size_t)193 << 20));
  char* sb = ws + ((size_t)192 << 20);
  float* gate = (float*)sb;                                       // 256 KiB
  int* topidx = (int*)(sb + 262144);                              // 16 KiB
  float* hlast = (float*)(sb + 262144 + 16384);                   // 32 KiB
  float* ctxbuf = (float*)(sb + 262144 + 16384 + 32768);          // 32 KiB
  float* qpart = (float*)(sb + 262144 + 16384 + 65536);           // 256 KiB
  unsigned short* H = A1;                                         // A1 dead after gemm2

  hipFuncSetAttribute(reinterpret_cast<const void*>(gemm256_kernel<512, 1024, 4, true, true>),
                      hipFuncAttributeMaxDynamicSharedMemorySize, 131072);
  hipFuncSetAttribute(reinterpret_cast<const void*>(gemm256_kernel<1024, 512, 2, false, false>),
                      hipFuncAttributeMaxDynamicSharedMemorySize, 131072);

  cvtwt_kernel<<<12096, 256, 0, stream>>>(emb, embb, w1, w2, w1t, w2t);
  gemm256_kernel<512, 1024, 4, true, true>
      <<<1024, 512, 131072, stream>>>(seq, embb, w1t, b1, A1);
  gemm256_kernel<1024, 512, 2, false, false>
      <<<512, 512, 131072, stream>>>(nullptr, A1, w2t, b2, FF);
  ln_gate_kernel<<<16384, 256, 0, stream>>>(seq, emb, FF, H, ln_g, ln_b, wg, bg, gate, hlast);
  topk_qpart_kernel<<<144, 256, 0, stream>>>(gate, topidx, hlast, wq, bq, qpart);
  attn_kernel<<<64, 256, 0, stream>>>(H, qpart, topidx, ctxbuf);
  out_part_kernel<<<1000, 256, 0, stream>>>(ctxbuf, wo, part);
  out_reduce_kernel<<<2000, 256, 0, stream>>>(part, bo, out);
}

// Round 11
// 243.112 us; speedup vs baseline: 1.4231x; 1.3603x over previous
//
#include <hip/hip_runtime.h>

typedef __bf16 bf16x8 __attribute__((ext_vector_type(8)));
typedef float f32x4 __attribute__((ext_vector_type(4)));
typedef unsigned short ushort8v __attribute__((ext_vector_type(8)));

#define NB 16
#define NT 4096
#define NV 32000
#define ND 512
#define NH 1024
#define NSLOTS 256

__device__ __forceinline__ float b2f(unsigned short u) {
  unsigned int x = ((unsigned int)u) << 16;
  return __builtin_bit_cast(float, x);
}
__device__ __forceinline__ unsigned short f2b(float f) {
  unsigned int x = __builtin_bit_cast(unsigned int, f);
  unsigned int r = (x + 0x7FFFu + ((x >> 16) & 1u)) >> 16;
  return (unsigned short)r;
}

#define GLOAD_LDS16(g, l)                                                              \
  __builtin_amdgcn_global_load_lds((const __attribute__((address_space(1))) void*)(g), \
                                   (__attribute__((address_space(3))) void*)(l), 16, 0, 0)
#define BARRIER() asm volatile("s_barrier" ::: "memory")
#define VMCNT(n) asm volatile("s_waitcnt vmcnt(" #n ")" ::: "memory")

// ---------------------------------------------------------------------------
// Fused elementwise prep: emb f32->bf16 (blocks <8000) and w1/w2 transpose+cvt.
// ---------------------------------------------------------------------------
__global__ __launch_bounds__(256) void cvtwt_kernel(
    const float* __restrict__ emb, unsigned short* __restrict__ embb,
    const float* __restrict__ w1, const float* __restrict__ w2,
    unsigned short* __restrict__ w1t, unsigned short* __restrict__ w2t) {
  const int blk = blockIdx.x;
  if (blk < 8000) {
    const long base = ((long)blk * 256 + threadIdx.x) * 8;
    float4 a = *(const float4*)&emb[base];
    float4 b = *(const float4*)&emb[base + 4];
    ushort8v o;
    o[0] = f2b(a.x); o[1] = f2b(a.y); o[2] = f2b(a.z); o[3] = f2b(a.w);
    o[4] = f2b(b.x); o[5] = f2b(b.y); o[6] = f2b(b.z); o[7] = f2b(b.w);
    *(ushort8v*)&embb[base] = o;
  } else {
    const int i = (blk - 8000) * 256 + threadIdx.x;
    if (i < ND * NH) {
      const int n = i >> 9, k = i & 511;
      w1t[i] = f2b(w1[k * NH + n]);
    } else {
      const int j = i - ND * NH;
      const int n = j >> 10, k = j & 1023;
      w2t[j] = f2b(w2[k * ND + n]);
    }
  }
}

// ---------------------------------------------------------------------------
// 256x256 bf16 MFMA GEMM over VOCAB rows (M = 32000 = 125 tiles), r9-best
// 4-phase counted-vmcnt schedule. BK=64, 8 waves (2M x 4N), per-wave 128x64
// out, 128 KiB LDS 2-buf, (row&7) XOR chunk swizzle (conflict-free), m204
// bijective XCD block swizzle (grid not divisible by 8). Counted waits:
// vmcnt(4) end P1 retires this tile's A1,A3; vmcnt(2) end P3 leaves next
// tile's A1,A3 in flight across the tile boundary.
// ---------------------------------------------------------------------------
template <int KDIM, int NLD, int NBN, bool RELU>
__global__ __launch_bounds__(512, 2) void gemm256_kernel(
    const unsigned short* __restrict__ Abase, const unsigned short* __restrict__ Bt,
    const float* __restrict__ bias, unsigned short* __restrict__ Out) {
  extern __shared__ unsigned short smraw[];  // 2 x (A 16384 | B 16384) shorts
  const int tid = threadIdx.x;
  const int lane = tid & 63;
  const int w = tid >> 6;   // 0..7
  const int wm = w >> 2;    // 0..1
  const int wn = w & 3;     // 0..3

  // m204 bijective XCD swizzle (works for any grid size)
  const int id = blockIdx.x;
  const int nwg = gridDim.x;
  const int q = nwg >> 3, r = nwg & 7;
  const int xcd = id & 7;
  const int swz = ((xcd < r) ? xcd * (q + 1) : r * (q + 1) + (xcd - r) * q) + (id >> 3);
  const int bm = swz / NBN;
  const int bn = swz % NBN;

  // Staging: tile matrix = 256 rows x 8 chunks(16B). Inst k covers rows
  // k*64 + (tid>>3); LDS slot (row,c) holds global chunk c ^ (row&7).
  const int srow = tid >> 3;                       // 0..63
  const int schunk = (tid & 7) ^ (srow & 7);
  const unsigned short* aptr[4];
  const unsigned short* bptr[4];
#pragma unroll
  for (int k = 0; k < 4; ++k) {
    const int row = k * 64 + srow;
    aptr[k] = Abase + (size_t)(bm * 256 + row) * KDIM + schunk * 8;
    bptr[k] = Bt + (size_t)(bn * 256 + row) * KDIM + schunk * 8;
  }

  const int fr = lane & 15;
  const int hi = lane >> 4;

  f32x4 acc[8][4] = {};
  bf16x8 bfr[4][2];  // B fragments, held across the tile's 4 phases

  auto stageA = [&](int buf, int k, int kt) {
    unsigned short* A = smraw + buf * 32768;
    GLOAD_LDS16(aptr[k] + kt * 64, &A[(k * 512 + w * 64) * 8]);
  };
  auto stageB = [&](int buf, int k, int kt) {
    unsigned short* B = smraw + buf * 32768 + 16384;
    GLOAD_LDS16(bptr[k] + kt * 64, &B[(k * 512 + w * 64) * 8]);
  };

  // Prologue: tile 0 into buf0, full drain.
#pragma unroll
  for (int k = 0; k < 4; ++k) stageB(0, k, 0);
#pragma unroll
  for (int k = 0; k < 4; ++k) stageA(0, k, 0);
  VMCNT(0);
  BARRIER();

#define LDFRAG(base, r_, kk) \
  __builtin_bit_cast(bf16x8, *(const ushort8v*)&(base)[(r_) * 64 + (((kk) * 4 + hi) ^ (fr & 7)) * 8])
#define MFMA_PHASE(j)                                                                   \
  __builtin_amdgcn_s_setprio(1);                                                        \
  _Pragma("unroll") for (int mm = 0; mm < 2; ++mm)                                      \
      _Pragma("unroll") for (int n = 0; n < 4; ++n)                                     \
          _Pragma("unroll") for (int kk = 0; kk < 2; ++kk)                              \
              acc[2 * (j) + mm][n] =                                                    \
                  __builtin_amdgcn_mfma_f32_16x16x32_bf16(af[mm][kk], bfr[n][kk],       \
                                                          acc[2 * (j) + mm][n], 0, 0, 0); \
  __builtin_amdgcn_s_setprio(0)

  constexpr int NKT = KDIM / 64;
  for (int t = 0; t < NKT; ++t) {
    const int cur = t & 1;
    const unsigned short* A = smraw + cur * 32768;
    const unsigned short* B = A + 16384;
    const bool hn = (t + 1 < NKT);
    const int nk = t + 1;
    bf16x8 af[2][2];
    // ---- phase 0: read bf(all)+af(m0,m1); stage B0,B1
#pragma unroll
    for (int n = 0; n < 4; ++n)
#pragma unroll
      for (int kk = 0; kk < 2; ++kk) bfr[n][kk] = LDFRAG(B, wn * 64 + n * 16 + fr, kk);
#pragma unroll
    for (int mm = 0; mm < 2; ++mm)
#pragma unroll
      for (int kk = 0; kk < 2; ++kk) af[mm][kk] = LDFRAG(A, wm * 128 + mm * 16 + fr, kk);
    if (hn) { stageB(cur ^ 1, 0, nk); stageB(cur ^ 1, 1, nk); }
    BARRIER();
    MFMA_PHASE(0);
    // ---- phase 1: read af(m2,m3); stage B2,B3; vmcnt(4) retires A1,A3 of this tile
#pragma unroll
    for (int mm = 0; mm < 2; ++mm)
#pragma unroll
      for (int kk = 0; kk < 2; ++kk)
        af[mm][kk] = LDFRAG(A, wm * 128 + (2 + mm) * 16 + fr, kk);
    if (hn) {
      stageB(cur ^ 1, 2, nk); stageB(cur ^ 1, 3, nk);
      VMCNT(4);
    } else {
      VMCNT(0);
    }
    BARRIER();
    MFMA_PHASE(1);
    // ---- phase 2: read af(m4,m5); stage A0,A2
#pragma unroll
    for (int mm = 0; mm < 2; ++mm)
#pragma unroll
      for (int kk = 0; kk < 2; ++kk)
        af[mm][kk] = LDFRAG(A, wm * 128 + (4 + mm) * 16 + fr, kk);
    if (hn) { stageA(cur ^ 1, 0, nk); stageA(cur ^ 1, 2, nk); }
    BARRIER();
    MFMA_PHASE(2);
    // ---- phase 3: read af(m6,m7); stage A1,A3; vmcnt(2) leaves A1,A3 in flight
#pragma unroll
    for (int mm = 0; mm < 2; ++mm)
#pragma unroll
      for (int kk = 0; kk < 2; ++kk)
        af[mm][kk] = LDFRAG(A, wm * 128 + (6 + mm) * 16 + fr, kk);
    if (hn) {
      stageA(cur ^ 1, 1, nk); stageA(cur ^ 1, 3, nk);
      VMCNT(2);
    }
    BARRIER();
    MFMA_PHASE(3);
  }
  __syncthreads();  // all reads done before C repack reuses LDS

  // Epilogue: bias (+relu); repack through LDS [128][264] in two row-halves.
  float bb[4];
#pragma unroll
  for (int n = 0; n < 4; ++n) bb[n] = bias[bn * 256 + wn * 64 + n * 16 + fr];
  unsigned short* C = smraw;
#pragma unroll
  for (int h = 0; h < 2; ++h) {
    if (h) __syncthreads();
    if (wm == h) {
#pragma unroll
      for (int m = 0; m < 8; ++m)
#pragma unroll
        for (int n = 0; n < 4; ++n)
#pragma unroll
          for (int i = 0; i < 4; ++i) {
            float v = acc[m][n][i] + bb[n];
            if constexpr (RELU) v = fmaxf(v, 0.f);
            C[(m * 16 + hi * 4 + i) * 264 + wn * 64 + n * 16 + fr] = f2b(v);
          }
    }
    __syncthreads();
#pragma unroll
    for (int it = 0; it < 8; ++it) {
      const int idx = it * 512 + tid;
      const int lrow = idx >> 5;
      const int pos = idx & 31;
      ushort8v v = *(const ushort8v*)&C[lrow * 264 + pos * 8];
      *(ushort8v*)&Out[(size_t)(bm * 256 + h * 128 + lrow) * (size_t)NLD + bn * 256 + pos * 8] = v;
    }
  }
#undef LDFRAG
#undef MFMA_PHASE
}

// ---------------------------------------------------------------------------
// Vocab-space residual + LayerNorm + gate (f32 math). One wave per vocab row.
// x = emb[v] + FFv[v]; h -> Hv (bf16); gatev[v] = sigmoid(h.wg+bg).
// hlast[b] (f32) written when v == seq[b*NT+NT-1] (16 uniform compares).
// ---------------------------------------------------------------------------
__global__ __launch_bounds__(256) void lnv_kernel(
    const float* __restrict__ emb, const unsigned short* __restrict__ FFv,
    unsigned short* __restrict__ Hv, const float* __restrict__ ln_g,
    const float* __restrict__ ln_b, const float* __restrict__ wg,
    const float* __restrict__ bgp, float* __restrict__ gatev,
    const int* __restrict__ seq, float* __restrict__ hlast) {
  const int lane = threadIdx.x & 63;
  const int w = threadIdx.x >> 6;
  const int v = blockIdx.x * 4 + w;
  const float* er = emb + (size_t)v * ND + lane * 8;
  ushort8v fv = *(const ushort8v*)&FFv[(size_t)v * ND + lane * 8];
  float4 e0 = *(const float4*)er, e1 = *(const float4*)(er + 4);
  float x[8] = {b2f(fv[0]) + e0.x, b2f(fv[1]) + e0.y, b2f(fv[2]) + e0.z, b2f(fv[3]) + e0.w,
                b2f(fv[4]) + e1.x, b2f(fv[5]) + e1.y, b2f(fv[6]) + e1.z, b2f(fv[7]) + e1.w};
  float s = 0.f, sq = 0.f;
#pragma unroll
  for (int j = 0; j < 8; ++j) {
    s += x[j];
    sq += x[j] * x[j];
  }
#pragma unroll
  for (int o = 32; o; o >>= 1) {
    s += __shfl_xor(s, o);
    sq += __shfl_xor(sq, o);
  }
  const float mu = s * (1.f / 512.f);
  const float var = sq * (1.f / 512.f) - mu * mu;
  const float rs = rsqrtf(var + 1e-5f);
  float gd = 0.f;
  float h[8];
  ushort8v hv;
#pragma unroll
  for (int j = 0; j < 8; ++j) {
    const int col = lane * 8 + j;
    h[j] = (x[j] - mu) * rs * ln_g[col] + ln_b[col];
    hv[j] = f2b(h[j]);
    gd += h[j] * wg[col];
  }
  *(ushort8v*)&Hv[(size_t)v * ND + lane * 8] = hv;
#pragma unroll
  for (int o = 32; o; o >>= 1) gd += __shfl_xor(gd, o);
  if (lane == 0) gatev[v] = 1.f / (1.f + expf(-(gd + bgp[0])));
  // last-token f32 h capture (uniform per-wave compares)
  for (int b = 0; b < NB; ++b) {
    if (seq[b * NT + NT - 1] == v) {
      float* hl = hlast + b * ND + lane * 8;
#pragma unroll
      for (int j = 0; j < 8; ++j) hl[j] = h[j];
    }
  }
}

// ---------------------------------------------------------------------------
// Merged: blocks 0..15 = per-batch top-256 radix select on gathered gatev;
// blocks 16..143 = qpart slices.
// ---------------------------------------------------------------------------
__global__ __launch_bounds__(256) void topk_qpart_kernel(
    const float* __restrict__ gatev, const int* __restrict__ seq,
    int* __restrict__ topidx, const float* __restrict__ hlast,
    const float* __restrict__ wq, const float* __restrict__ bq,
    float* __restrict__ qpart) {
  __shared__ unsigned int keys[NT];
  __shared__ int cnt;
  __shared__ int scan[256];
  const int tid = threadIdx.x;
  if (blockIdx.x >= 16) {
    const int blk = blockIdx.x - 16;
    const int b = blk >> 3, s = blk & 7;
    const int d0 = s * 64;
    float a0 = 0.f, a1 = 0.f;
#pragma unroll 4
    for (int dd = 0; dd < 64; ++dd) {
      const float hv = hlast[b * ND + d0 + dd];
      a0 += hv * wq[(size_t)(d0 + dd) * ND + tid];
      a1 += hv * wq[(size_t)(d0 + dd) * ND + tid + 256];
    }
    if (s == 0) {
      a0 += bq[tid];
      a1 += bq[tid + 256];
    }
    float* qp = qpart + ((size_t)b * 8 + s) * ND;
    qp[tid] = a0;
    qp[tid + 256] = a1;
    return;
  }
  const int b = blockIdx.x;
  const int* sq_ = seq + (size_t)b * NT;
  for (int i = tid; i < NT; i += 256)
    keys[i] = __builtin_bit_cast(unsigned int, gatev[sq_[i]]);
  __syncthreads();
  unsigned int K = 0u;
  for (int bit = 31; bit >= 0; --bit) {
    const unsigned int cand = K | (1u << bit);
    if (tid == 0) cnt = 0;
    __syncthreads();
    int c = 0;
    for (int i = tid * 16; i < tid * 16 + 16; ++i) c += (keys[i] >= cand) ? 1 : 0;
    if (c) atomicAdd(&cnt, c);
    __syncthreads();
    const int cn = cnt;
    __syncthreads();
    if (cn >= NSLOTS) K = cand;
  }
  int gcnt = 0, ecnt = 0;
  for (int i = tid * 16; i < tid * 16 + 16; ++i) {
    gcnt += (keys[i] > K) ? 1 : 0;
    ecnt += (keys[i] == K) ? 1 : 0;
  }
  scan[tid] = gcnt;
  __syncthreads();
  for (int off = 1; off < 256; off <<= 1) {
    int v2 = (tid >= off) ? scan[tid - off] : 0;
    __syncthreads();
    scan[tid] += v2;
    __syncthreads();
  }
  const int gi = scan[tid];
  const int tot_gt = scan[255];
  __syncthreads();
  scan[tid] = ecnt;
  __syncthreads();
  for (int off = 1; off < 256; off <<= 1) {
    int v2 = (tid >= off) ? scan[tid - off] : 0;
    __syncthreads();
    scan[tid] += v2;
    __syncthreads();
  }
  const int ei = scan[tid];
  int gpos = gi - gcnt;
  int epos = tot_gt + (ei - ecnt);
  int* outp = topidx + b * NSLOTS;
  for (int i = tid * 16; i < tid * 16 + 16; ++i) {
    if (keys[i] > K) {
      outp[gpos++] = i;
    } else if (keys[i] == K) {
      if (epos < NSLOTS) outp[epos] = i;
      epos++;
    }
  }
}

// ---------------------------------------------------------------------------
// Fused scores + softmax + ctx. 64 blocks = 16 batches x 4 d-chunks of 128.
// Memory rows come from Hv via vocab-id indirection.
// ---------------------------------------------------------------------------
__global__ __launch_bounds__(256) void attn_kernel(
    const unsigned short* __restrict__ Hv, const int* __restrict__ seq,
    const float* __restrict__ qpart, const int* __restrict__ topidx,
    float* __restrict__ ctx) {
  __shared__ float qs[512];
  __shared__ float attnv[256];
  __shared__ int idxs[256];  // vocab ids of selected slots
  __shared__ float red[4];
  __shared__ float part[2][128];
  const int blk = blockIdx.x;
  const int b = blk >> 2, dc = blk & 3;
  const int tid = threadIdx.x;
  const int lane = tid & 63, wv = tid >> 6;
  {
    float a0 = 0.f, a1 = 0.f;
#pragma unroll
    for (int s = 0; s < 8; ++s) {
      const float* qp = qpart + ((size_t)b * 8 + s) * ND;
      a0 += qp[tid];
      a1 += qp[tid + 256];
    }
    qs[tid] = a0;
    qs[tid + 256] = a1;
  }
  idxs[tid] = seq[(size_t)b * NT + topidx[b * 256 + tid]];
  __syncthreads();
  const unsigned short* hr = Hv + (size_t)idxs[tid] * ND;
  float sc = 0.f;
  for (int d0 = 0; d0 < 512; d0 += 8) {
    ushort8v hv = *(const ushort8v*)&hr[d0];
#pragma unroll
    for (int j = 0; j < 8; ++j) sc += b2f(hv[j]) * qs[d0 + j];
  }
  float m = sc;
#pragma unroll
  for (int o = 32; o; o >>= 1) m = fmaxf(m, __shfl_xor(m, o));
  if (lane == 0) red[wv] = m;
  __syncthreads();
  m = fmaxf(fmaxf(red[0], red[1]), fmaxf(red[2], red[3]));
  __syncthreads();
  const float e = expf(sc - m);
  float ssum = e;
#pragma unroll
  for (int o = 32; o; o >>= 1) ssum += __shfl_xor(ssum, o);
  if (lane == 0) red[wv] = ssum;
  __syncthreads();
  ssum = red[0] + red[1] + red[2] + red[3];
  attnv[tid] = e / ssum;
  __syncthreads();
  const int d = dc * 128 + (tid & 127);
  const int kh = tid >> 7;
  float c = 0.f;
#pragma unroll 4
  for (int k2 = 0; k2 < 128; ++k2) {
    const int k = kh * 128 + k2;
    c += attnv[k] * b2f(Hv[(size_t)idxs[k] * ND + d]);
  }
  part[kh][tid & 127] = c;
  __syncthreads();
  if (tid < 128) ctx[b * 512 + dc * 128 + tid] = part[0][tid] + part[1][tid];
}

// ---------------------------------------------------------------------------
// Out-projection stage 1: part[s][b][v] = sum_{d in slice s(64)} ctx[b][d]*wo[d][v]
// ---------------------------------------------------------------------------
__global__ __launch_bounds__(256) void out_part_kernel(const float* __restrict__ ctx,
                                                       const float* __restrict__ wo,
                                                       float* __restrict__ part) {
  const int blk = blockIdx.x;
  const int ct = blk % 125, s = blk / 125;
  const int v = ct * 256 + threadIdx.x;
  const int d0 = s * 64;
  const float* wp = wo + (size_t)d0 * NV + v;
  float acc[16] = {};
#pragma unroll 4
  for (int dd = 0; dd < 64; ++dd) {
    const float wv = wp[(size_t)dd * NV];
#pragma unroll
    for (int bb = 0; bb < 16; ++bb) acc[bb] += ctx[bb * ND + d0 + dd] * wv;
  }
  float* pp = part + (size_t)s * NB * NV + v;
#pragma unroll
  for (int bb = 0; bb < 16; ++bb) pp[(size_t)bb * NV] = acc[bb];
}

// ---------------------------------------------------------------------------
// Out-projection stage 2: out[b][v] = sum_s part[s][b][v] + bo[v]
// ---------------------------------------------------------------------------
__global__ __launch_bounds__(256) void out_reduce_kernel(const float* __restrict__ part,
                                                         const float* __restrict__ bo,
                                                         float* __restrict__ out) {
  const int i = blockIdx.x * 256 + threadIdx.x;
  const int b = i / NV;
  const int v = i - b * NV;
  float a = bo[v];
#pragma unroll
  for (int s = 0; s < 8; ++s) a += part[(size_t)s * NB * NV + i];
  out[i] = a;
}

// ---------------------------------------------------------------------------
// Workspace layout (vocab-space; total ~181 MiB, no risky aliasing):
//   A1v   @ 0        : 32000x1024 bf16 = 62.5 MiB
//   FFv   @ 64 MiB   : 32000x512 bf16 = 31.25 MiB
//   embb  @ 96 MiB   : 32000x512 bf16 = 31.25 MiB
//   Hv    @ 128 MiB  : 32000x512 bf16 = 31.25 MiB
//   part  @ 160 MiB  : 8x16x32000 f32 = 16.4 MB
//   w1t   @ 177 MiB, w2t @ 178 MiB, smalls @ 180 MiB
// ---------------------------------------------------------------------------
extern "C" void kernel_launch(void* const* d_in, const int* in_sizes, int n_in,
                              void* d_out, int out_size, void* d_ws, size_t ws_size,
                              hipStream_t stream) {
  const int* seq = (const int*)d_in[0];
  const float* emb = (const float*)d_in[1];
  const float* w1 = (const float*)d_in[2];
  const float* b1 = (const float*)d_in[3];
  const float* w2 = (const float*)d_in[4];
  const float* b2 = (const float*)d_in[5];
  const float* ln_g = (const float*)d_in[6];
  const float* ln_b = (const float*)d_in[7];
  const float* wg = (const float*)d_in[8];
  const float* bg = (const float*)d_in[9];
  const float* wq = (const float*)d_in[10];
  const float* bq = (const float*)d_in[11];
  const float* wo = (const float*)d_in[12];
  const float* bo = (const float*)d_in[13];
  float* out = (float*)d_out;

  char* ws = (char*)d_ws;
  unsigned short* A1v = (unsigned short*)ws;                        // 62.5 MiB
  unsigned short* FFv = (unsigned short*)(ws + ((size_t)64 << 20)); // 31.25 MiB
  unsigned short* embb = (unsigned short*)(ws + ((size_t)96 << 20));
  unsigned short* Hv = (unsigned short*)(ws + ((size_t)128 << 20));
  float* part = (float*)(ws + ((size_t)160 << 20));                 // 16.4 MB
  unsigned short* w1t = (unsigned short*)(ws + ((size_t)177 << 20));
  unsigned short* w2t = (unsigned short*)(ws + ((size_t)178 << 20));
  char* sb = ws + ((size_t)180 << 20);
  float* gatev = (float*)sb;                                        // 128 KiB
  int* topidx = (int*)(sb + 131072);                                // 16 KiB
  float* hlast = (float*)(sb + 131072 + 16384);                     // 32 KiB
  float* ctxbuf = (float*)(sb + 131072 + 16384 + 32768);            // 32 KiB
  float* qpart = (float*)(sb + 131072 + 16384 + 65536);             // 256 KiB

  hipFuncSetAttribute(reinterpret_cast<const void*>(gemm256_kernel<512, 1024, 4, true>),
                      hipFuncAttributeMaxDynamicSharedMemorySize, 131072);
  hipFuncSetAttribute(reinterpret_cast<const void*>(gemm256_kernel<1024, 512, 2, false>),
                      hipFuncAttributeMaxDynamicSharedMemorySize, 131072);

  cvtwt_kernel<<<12096, 256, 0, stream>>>(emb, embb, w1, w2, w1t, w2t);
  // FF over vocab rows (32000 = 125 x 256)
  gemm256_kernel<512, 1024, 4, true>
      <<<500, 512, 131072, stream>>>(embb, w1t, b1, A1v);
  gemm256_kernel<1024, 512, 2, false>
      <<<250, 512, 131072, stream>>>(A1v, w2t, b2, FFv);
  lnv_kernel<<<8000, 256, 0, stream>>>(emb, FFv, Hv, ln_g, ln_b, wg, bg, gatev, seq, hlast);
  topk_qpart_kernel<<<144, 256, 0, stream>>>(gatev, seq, topidx, hlast, wq, bq, qpart);
  attn_kernel<<<64, 256, 0, stream>>>(Hv, seq, qpart, topidx, ctxbuf);
  out_part_kernel<<<1000, 256, 0, stream>>>(ctxbuf, wo, part);
  out_reduce_kernel<<<2000, 256, 0, stream>>>(part, bo, out);
}

// Round 12
// 196.283 us; speedup vs baseline: 1.7627x; 1.2386x over previous
//
#include <hip/hip_runtime.h>

typedef __bf16 bf16x8 __attribute__((ext_vector_type(8)));
typedef float f32x4 __attribute__((ext_vector_type(4)));
typedef unsigned short ushort8v __attribute__((ext_vector_type(8)));

#define NB 16
#define NT 4096
#define NV 32000
#define ND 512
#define NH 1024
#define NSLOTS 256

__device__ __forceinline__ float b2f(unsigned short u) {
  unsigned int x = ((unsigned int)u) << 16;
  return __builtin_bit_cast(float, x);
}
__device__ __forceinline__ unsigned short f2b(float f) {
  unsigned int x = __builtin_bit_cast(unsigned int, f);
  unsigned int r = (x + 0x7FFFu + ((x >> 16) & 1u)) >> 16;
  return (unsigned short)r;
}

#define GLOAD_LDS16(g, l)                                                              \
  __builtin_amdgcn_global_load_lds((const __attribute__((address_space(1))) void*)(g), \
                                   (__attribute__((address_space(3))) void*)(l), 16, 0, 0)
#define BARRIER() asm volatile("s_barrier" ::: "memory")
#define VMCNT(n) asm volatile("s_waitcnt vmcnt(" #n ")" ::: "memory")

// ---------------------------------------------------------------------------
// Fused elementwise prep: emb f32->bf16 (blocks <8000) and w1/w2 transpose+cvt.
// ---------------------------------------------------------------------------
__global__ __launch_bounds__(256) void cvtwt_kernel(
    const float* __restrict__ emb, unsigned short* __restrict__ embb,
    const float* __restrict__ w1, const float* __restrict__ w2,
    unsigned short* __restrict__ w1t, unsigned short* __restrict__ w2t) {
  const int blk = blockIdx.x;
  if (blk < 8000) {
    const long base = ((long)blk * 256 + threadIdx.x) * 8;
    float4 a = *(const float4*)&emb[base];
    float4 b = *(const float4*)&emb[base + 4];
    ushort8v o;
    o[0] = f2b(a.x); o[1] = f2b(a.y); o[2] = f2b(a.z); o[3] = f2b(a.w);
    o[4] = f2b(b.x); o[5] = f2b(b.y); o[6] = f2b(b.z); o[7] = f2b(b.w);
    *(ushort8v*)&embb[base] = o;
  } else {
    const int i = (blk - 8000) * 256 + threadIdx.x;
    if (i < ND * NH) {
      const int n = i >> 9, k = i & 511;
      w1t[i] = f2b(w1[k * NH + n]);
    } else {
      const int j = i - ND * NH;
      const int n = j >> 10, k = j & 1023;
      w2t[j] = f2b(w2[k * ND + n]);
    }
  }
}

// ---------------------------------------------------------------------------
// 256x256 bf16 MFMA GEMM over VOCAB rows (M = 32000 = 125 tiles), r9-best
// 4-phase counted-vmcnt schedule. BK=64, 8 waves (2M x 4N), per-wave 128x64
// out, 128 KiB LDS 2-buf, (row&7) XOR chunk swizzle (conflict-free), m204
// bijective XCD block swizzle. Counted waits: vmcnt(4) end P1, vmcnt(2) end P3.
// ---------------------------------------------------------------------------
template <int KDIM, int NLD, int NBN, bool RELU>
__global__ __launch_bounds__(512, 2) void gemm256_kernel(
    const unsigned short* __restrict__ Abase, const unsigned short* __restrict__ Bt,
    const float* __restrict__ bias, unsigned short* __restrict__ Out) {
  extern __shared__ unsigned short smraw[];  // 2 x (A 16384 | B 16384) shorts
  const int tid = threadIdx.x;
  const int lane = tid & 63;
  const int w = tid >> 6;   // 0..7
  const int wm = w >> 2;    // 0..1
  const int wn = w & 3;     // 0..3

  // m204 bijective XCD swizzle (works for any grid size)
  const int id = blockIdx.x;
  const int nwg = gridDim.x;
  const int q = nwg >> 3, r = nwg & 7;
  const int xcd = id & 7;
  const int swz = ((xcd < r) ? xcd * (q + 1) : r * (q + 1) + (xcd - r) * q) + (id >> 3);
  const int bm = swz / NBN;
  const int bn = swz % NBN;

  const int srow = tid >> 3;                       // 0..63
  const int schunk = (tid & 7) ^ (srow & 7);
  const unsigned short* aptr[4];
  const unsigned short* bptr[4];
#pragma unroll
  for (int k = 0; k < 4; ++k) {
    const int row = k * 64 + srow;
    aptr[k] = Abase + (size_t)(bm * 256 + row) * KDIM + schunk * 8;
    bptr[k] = Bt + (size_t)(bn * 256 + row) * KDIM + schunk * 8;
  }

  const int fr = lane & 15;
  const int hi = lane >> 4;

  f32x4 acc[8][4] = {};
  bf16x8 bfr[4][2];  // B fragments, held across the tile's 4 phases

  auto stageA = [&](int buf, int k, int kt) {
    unsigned short* A = smraw + buf * 32768;
    GLOAD_LDS16(aptr[k] + kt * 64, &A[(k * 512 + w * 64) * 8]);
  };
  auto stageB = [&](int buf, int k, int kt) {
    unsigned short* B = smraw + buf * 32768 + 16384;
    GLOAD_LDS16(bptr[k] + kt * 64, &B[(k * 512 + w * 64) * 8]);
  };

  // Prologue: tile 0 into buf0, full drain.
#pragma unroll
  for (int k = 0; k < 4; ++k) stageB(0, k, 0);
#pragma unroll
  for (int k = 0; k < 4; ++k) stageA(0, k, 0);
  VMCNT(0);
  BARRIER();

#define LDFRAG(base, r_, kk) \
  __builtin_bit_cast(bf16x8, *(const ushort8v*)&(base)[(r_) * 64 + (((kk) * 4 + hi) ^ (fr & 7)) * 8])
#define MFMA_PHASE(j)                                                                   \
  __builtin_amdgcn_s_setprio(1);                                                        \
  _Pragma("unroll") for (int mm = 0; mm < 2; ++mm)                                      \
      _Pragma("unroll") for (int n = 0; n < 4; ++n)                                     \
          _Pragma("unroll") for (int kk = 0; kk < 2; ++kk)                              \
              acc[2 * (j) + mm][n] =                                                    \
                  __builtin_amdgcn_mfma_f32_16x16x32_bf16(af[mm][kk], bfr[n][kk],       \
                                                          acc[2 * (j) + mm][n], 0, 0, 0); \
  __builtin_amdgcn_s_setprio(0)

  constexpr int NKT = KDIM / 64;
  for (int t = 0; t < NKT; ++t) {
    const int cur = t & 1;
    const unsigned short* A = smraw + cur * 32768;
    const unsigned short* B = A + 16384;
    const bool hn = (t + 1 < NKT);
    const int nk = t + 1;
    bf16x8 af[2][2];
    // ---- phase 0: read bf(all)+af(m0,m1); stage B0,B1
#pragma unroll
    for (int n = 0; n < 4; ++n)
#pragma unroll
      for (int kk = 0; kk < 2; ++kk) bfr[n][kk] = LDFRAG(B, wn * 64 + n * 16 + fr, kk);
#pragma unroll
    for (int mm = 0; mm < 2; ++mm)
#pragma unroll
      for (int kk = 0; kk < 2; ++kk) af[mm][kk] = LDFRAG(A, wm * 128 + mm * 16 + fr, kk);
    if (hn) { stageB(cur ^ 1, 0, nk); stageB(cur ^ 1, 1, nk); }
    BARRIER();
    MFMA_PHASE(0);
    // ---- phase 1: read af(m2,m3); stage B2,B3; vmcnt(4) retires A1,A3 of this tile
#pragma unroll
    for (int mm = 0; mm < 2; ++mm)
#pragma unroll
      for (int kk = 0; kk < 2; ++kk)
        af[mm][kk] = LDFRAG(A, wm * 128 + (2 + mm) * 16 + fr, kk);
    if (hn) {
      stageB(cur ^ 1, 2, nk); stageB(cur ^ 1, 3, nk);
      VMCNT(4);
    } else {
      VMCNT(0);
    }
    BARRIER();
    MFMA_PHASE(1);
    // ---- phase 2: read af(m4,m5); stage A0,A2
#pragma unroll
    for (int mm = 0; mm < 2; ++mm)
#pragma unroll
      for (int kk = 0; kk < 2; ++kk)
        af[mm][kk] = LDFRAG(A, wm * 128 + (4 + mm) * 16 + fr, kk);
    if (hn) { stageA(cur ^ 1, 0, nk); stageA(cur ^ 1, 2, nk); }
    BARRIER();
    MFMA_PHASE(2);
    // ---- phase 3: read af(m6,m7); stage A1,A3; vmcnt(2) leaves A1,A3 in flight
#pragma unroll
    for (int mm = 0; mm < 2; ++mm)
#pragma unroll
      for (int kk = 0; kk < 2; ++kk)
        af[mm][kk] = LDFRAG(A, wm * 128 + (6 + mm) * 16 + fr, kk);
    if (hn) {
      stageA(cur ^ 1, 1, nk); stageA(cur ^ 1, 3, nk);
      VMCNT(2);
    }
    BARRIER();
    MFMA_PHASE(3);
  }
  __syncthreads();  // all reads done before C repack reuses LDS

  // Epilogue: bias (+relu); repack through LDS [128][264] in two row-halves.
  float bb[4];
#pragma unroll
  for (int n = 0; n < 4; ++n) bb[n] = bias[bn * 256 + wn * 64 + n * 16 + fr];
  unsigned short* C = smraw;
#pragma unroll
  for (int h = 0; h < 2; ++h) {
    if (h) __syncthreads();
    if (wm == h) {
#pragma unroll
      for (int m = 0; m < 8; ++m)
#pragma unroll
        for (int n = 0; n < 4; ++n)
#pragma unroll
          for (int i = 0; i < 4; ++i) {
            float v = acc[m][n][i] + bb[n];
            if constexpr (RELU) v = fmaxf(v, 0.f);
            C[(m * 16 + hi * 4 + i) * 264 + wn * 64 + n * 16 + fr] = f2b(v);
          }
    }
    __syncthreads();
#pragma unroll
    for (int it = 0; it < 8; ++it) {
      const int idx = it * 512 + tid;
      const int lrow = idx >> 5;
      const int pos = idx & 31;
      ushort8v v = *(const ushort8v*)&C[lrow * 264 + pos * 8];
      *(ushort8v*)&Out[(size_t)(bm * 256 + h * 128 + lrow) * (size_t)NLD + bn * 256 + pos * 8] = v;
    }
  }
#undef LDFRAG
#undef MFMA_PHASE
}

// ---------------------------------------------------------------------------
// Vocab-space residual + LayerNorm + gate (f32 math). One wave per vocab row.
// ---------------------------------------------------------------------------
__global__ __launch_bounds__(256) void lnv_kernel(
    const float* __restrict__ emb, const unsigned short* __restrict__ FFv,
    unsigned short* __restrict__ Hv, const float* __restrict__ ln_g,
    const float* __restrict__ ln_b, const float* __restrict__ wg,
    const float* __restrict__ bgp, float* __restrict__ gatev,
    const int* __restrict__ seq, float* __restrict__ hlast) {
  const int lane = threadIdx.x & 63;
  const int w = threadIdx.x >> 6;
  const int v = blockIdx.x * 4 + w;
  const float* er = emb + (size_t)v * ND + lane * 8;
  ushort8v fv = *(const ushort8v*)&FFv[(size_t)v * ND + lane * 8];
  float4 e0 = *(const float4*)er, e1 = *(const float4*)(er + 4);
  float x[8] = {b2f(fv[0]) + e0.x, b2f(fv[1]) + e0.y, b2f(fv[2]) + e0.z, b2f(fv[3]) + e0.w,
                b2f(fv[4]) + e1.x, b2f(fv[5]) + e1.y, b2f(fv[6]) + e1.z, b2f(fv[7]) + e1.w};
  float s = 0.f, sq = 0.f;
#pragma unroll
  for (int j = 0; j < 8; ++j) {
    s += x[j];
    sq += x[j] * x[j];
  }
#pragma unroll
  for (int o = 32; o; o >>= 1) {
    s += __shfl_xor(s, o);
    sq += __shfl_xor(sq, o);
  }
  const float mu = s * (1.f / 512.f);
  const float var = sq * (1.f / 512.f) - mu * mu;
  const float rs = rsqrtf(var + 1e-5f);
  float gd = 0.f;
  float h[8];
  ushort8v hv;
#pragma unroll
  for (int j = 0; j < 8; ++j) {
    const int col = lane * 8 + j;
    h[j] = (x[j] - mu) * rs * ln_g[col] + ln_b[col];
    hv[j] = f2b(h[j]);
    gd += h[j] * wg[col];
  }
  *(ushort8v*)&Hv[(size_t)v * ND + lane * 8] = hv;
#pragma unroll
  for (int o = 32; o; o >>= 1) gd += __shfl_xor(gd, o);
  if (lane == 0) gatev[v] = 1.f / (1.f + expf(-(gd + bgp[0])));
  for (int b = 0; b < NB; ++b) {
    if (seq[b * NT + NT - 1] == v) {
      float* hl = hlast + b * ND + lane * 8;
#pragma unroll
      for (int j = 0; j < 8; ++j) hl[j] = h[j];
    }
  }
}

// ---------------------------------------------------------------------------
// Merged: blocks 0..15 = per-batch top-256 radix select (register-resident
// keys, wave-reduce counts, 1 barrier/bit via double-buffered wave sums,
// packed (gcnt<<16)|ecnt scan); blocks 16..143 = qpart slices.
// Same K and same emitted set/order as the r11 version (determinism canary).
// ---------------------------------------------------------------------------
__global__ __launch_bounds__(256) void topk_qpart_kernel(
    const float* __restrict__ gatev, const int* __restrict__ seq,
    int* __restrict__ topidx, const float* __restrict__ hlast,
    const float* __restrict__ wq, const float* __restrict__ bq,
    float* __restrict__ qpart) {
  __shared__ int wsum[2][4];
  __shared__ unsigned int scanbuf[256];
  const int tid = threadIdx.x;
  if (blockIdx.x >= 16) {
    const int blk = blockIdx.x - 16;
    const int b = blk >> 3, s = blk & 7;
    const int d0 = s * 64;
    float a0 = 0.f, a1 = 0.f;
#pragma unroll 4
    for (int dd = 0; dd < 64; ++dd) {
      const float hv = hlast[b * ND + d0 + dd];
      a0 += hv * wq[(size_t)(d0 + dd) * ND + tid];
      a1 += hv * wq[(size_t)(d0 + dd) * ND + tid + 256];
    }
    if (s == 0) {
      a0 += bq[tid];
      a1 += bq[tid + 256];
    }
    float* qp = qpart + ((size_t)b * 8 + s) * ND;
    qp[tid] = a0;
    qp[tid + 256] = a1;
    return;
  }
  const int b = blockIdx.x;
  const int wv = tid >> 6;
  const int lane = tid & 63;
  const int* sq_ = seq + (size_t)b * NT;
  const int base = tid * 16;
  // Keys in registers (16/thread, same ownership as r11's keys[tid*16+j]).
  unsigned int kreg[16];
#pragma unroll
  for (int j = 0; j < 16; ++j)
    kreg[j] = __builtin_bit_cast(unsigned int, gatev[sq_[base + j]]);

  unsigned int K = 0u;
  for (int bit = 31; bit >= 0; --bit) {
    const unsigned int cand = K | (1u << bit);
    int c = 0;
#pragma unroll
    for (int j = 0; j < 16; ++j) c += (kreg[j] >= cand) ? 1 : 0;
#pragma unroll
    for (int o = 32; o; o >>= 1) c += __shfl_xor(c, o);
    const int par = bit & 1;
    if (lane == 0) wsum[par][wv] = c;
    __syncthreads();
    const int tot = wsum[par][0] + wsum[par][1] + wsum[par][2] + wsum[par][3];
    if (tot >= NSLOTS) K = cand;
    // next iteration writes wsum[par^1]; double-buffer removes the WAR barrier
  }
  int gcnt = 0, ecnt = 0;
#pragma unroll
  for (int j = 0; j < 16; ++j) {
    gcnt += (kreg[j] > K) ? 1 : 0;
    ecnt += (kreg[j] == K) ? 1 : 0;
  }
  __syncthreads();  // wsum reads done before scanbuf phase (different array; cheap safety)
  scanbuf[tid] = ((unsigned int)gcnt << 16) | (unsigned int)ecnt;
  __syncthreads();
  for (int off = 1; off < 256; off <<= 1) {
    unsigned int v2 = (tid >= off) ? scanbuf[tid - off] : 0u;
    __syncthreads();
    scanbuf[tid] += v2;
    __syncthreads();
  }
  const unsigned int my = scanbuf[tid];
  const unsigned int tot = scanbuf[255];
  const int gi = (int)(my >> 16);
  const int ei = (int)(my & 0xFFFFu);
  const int tot_gt = (int)(tot >> 16);
  int gpos = gi - gcnt;
  int epos = tot_gt + (ei - ecnt);
  int* outp = topidx + b * NSLOTS;
#pragma unroll
  for (int j = 0; j < 16; ++j) {
    if (kreg[j] > K) {
      outp[gpos++] = base + j;
    } else if (kreg[j] == K) {
      if (epos < NSLOTS) outp[epos] = base + j;
      epos++;
    }
  }
}

// ---------------------------------------------------------------------------
// Fused scores + softmax + ctx. 64 blocks = 16 batches x 4 d-chunks of 128.
// Memory rows come from Hv via vocab-id indirection.
// ---------------------------------------------------------------------------
__global__ __launch_bounds__(256) void attn_kernel(
    const unsigned short* __restrict__ Hv, const int* __restrict__ seq,
    const float* __restrict__ qpart, const int* __restrict__ topidx,
    float* __restrict__ ctx) {
  __shared__ float qs[512];
  __shared__ float attnv[256];
  __shared__ int idxs[256];  // vocab ids of selected slots
  __shared__ float red[4];
  __shared__ float part[2][128];
  const int blk = blockIdx.x;
  const int b = blk >> 2, dc = blk & 3;
  const int tid = threadIdx.x;
  const int lane = tid & 63, wv = tid >> 6;
  {
    float a0 = 0.f, a1 = 0.f;
#pragma unroll
    for (int s = 0; s < 8; ++s) {
      const float* qp = qpart + ((size_t)b * 8 + s) * ND;
      a0 += qp[tid];
      a1 += qp[tid + 256];
    }
    qs[tid] = a0;
    qs[tid + 256] = a1;
  }
  idxs[tid] = seq[(size_t)b * NT + topidx[b * 256 + tid]];
  __syncthreads();
  const unsigned short* hr = Hv + (size_t)idxs[tid] * ND;
  float sc = 0.f;
  for (int d0 = 0; d0 < 512; d0 += 8) {
    ushort8v hv = *(const ushort8v*)&hr[d0];
#pragma unroll
    for (int j = 0; j < 8; ++j) sc += b2f(hv[j]) * qs[d0 + j];
  }
  float m = sc;
#pragma unroll
  for (int o = 32; o; o >>= 1) m = fmaxf(m, __shfl_xor(m, o));
  if (lane == 0) red[wv] = m;
  __syncthreads();
  m = fmaxf(fmaxf(red[0], red[1]), fmaxf(red[2], red[3]));
  __syncthreads();
  const float e = expf(sc - m);
  float ssum = e;
#pragma unroll
  for (int o = 32; o; o >>= 1) ssum += __shfl_xor(ssum, o);
  if (lane == 0) red[wv] = ssum;
  __syncthreads();
  ssum = red[0] + red[1] + red[2] + red[3];
  attnv[tid] = e / ssum;
  __syncthreads();
  const int d = dc * 128 + (tid & 127);
  const int kh = tid >> 7;
  float c = 0.f;
#pragma unroll 4
  for (int k2 = 0; k2 < 128; ++k2) {
    const int k = kh * 128 + k2;
    c += attnv[k] * b2f(Hv[(size_t)idxs[k] * ND + d]);
  }
  part[kh][tid & 127] = c;
  __syncthreads();
  if (tid < 128) ctx[b * 512 + dc * 128 + tid] = part[0][tid] + part[1][tid];
}

// ---------------------------------------------------------------------------
// Out-projection stage 1: part[s][b][v] = sum_{d in slice s(64)} ctx[b][d]*wo[d][v]
// ---------------------------------------------------------------------------
__global__ __launch_bounds__(256) void out_part_kernel(const float* __restrict__ ctx,
                                                       const float* __restrict__ wo,
                                                       float* __restrict__ part) {
  const int blk = blockIdx.x;
  const int ct = blk % 125, s = blk / 125;
  const int v = ct * 256 + threadIdx.x;
  const int d0 = s * 64;
  const float* wp = wo + (size_t)d0 * NV + v;
  float acc[16] = {};
#pragma unroll 4
  for (int dd = 0; dd < 64; ++dd) {
    const float wv = wp[(size_t)dd * NV];
#pragma unroll
    for (int bb = 0; bb < 16; ++bb) acc[bb] += ctx[bb * ND + d0 + dd] * wv;
  }
  float* pp = part + (size_t)s * NB * NV + v;
#pragma unroll
  for (int bb = 0; bb < 16; ++bb) pp[(size_t)bb * NV] = acc[bb];
}

// ---------------------------------------------------------------------------
// Out-projection stage 2: out[b][v] = sum_s part[s][b][v] + bo[v]
// ---------------------------------------------------------------------------
__global__ __launch_bounds__(256) void out_reduce_kernel(const float* __restrict__ part,
                                                         const float* __restrict__ bo,
                                                         float* __restrict__ out) {
  const int i = blockIdx.x * 256 + threadIdx.x;
  const int b = i / NV;
  const int v = i - b * NV;
  float a = bo[v];
#pragma unroll
  for (int s = 0; s < 8; ++s) a += part[(size_t)s * NB * NV + i];
  out[i] = a;
}

// ---------------------------------------------------------------------------
// Workspace layout (vocab-space; total ~181 MiB):
//   A1v   @ 0        : 32000x1024 bf16 = 62.5 MiB
//   FFv   @ 64 MiB   : 31.25 MiB
//   embb  @ 96 MiB   : 31.25 MiB
//   Hv    @ 128 MiB  : 31.25 MiB
//   part  @ 160 MiB  : 16.4 MB
//   w1t   @ 177 MiB, w2t @ 178 MiB, smalls @ 180 MiB
// ---------------------------------------------------------------------------
extern "C" void kernel_launch(void* const* d_in, const int* in_sizes, int n_in,
                              void* d_out, int out_size, void* d_ws, size_t ws_size,
                              hipStream_t stream) {
  const int* seq = (const int*)d_in[0];
  const float* emb = (const float*)d_in[1];
  const float* w1 = (const float*)d_in[2];
  const float* b1 = (const float*)d_in[3];
  const float* w2 = (const float*)d_in[4];
  const float* b2 = (const float*)d_in[5];
  const float* ln_g = (const float*)d_in[6];
  const float* ln_b = (const float*)d_in[7];
  const float* wg = (const float*)d_in[8];
  const float* bg = (const float*)d_in[9];
  const float* wq = (const float*)d_in[10];
  const float* bq = (const float*)d_in[11];
  const float* wo = (const float*)d_in[12];
  const float* bo = (const float*)d_in[13];
  float* out = (float*)d_out;

  char* ws = (char*)d_ws;
  unsigned short* A1v = (unsigned short*)ws;                        // 62.5 MiB
  unsigned short* FFv = (unsigned short*)(ws + ((size_t)64 << 20)); // 31.25 MiB
  unsigned short* embb = (unsigned short*)(ws + ((size_t)96 << 20));
  unsigned short* Hv = (unsigned short*)(ws + ((size_t)128 << 20));
  float* part = (float*)(ws + ((size_t)160 << 20));                 // 16.4 MB
  unsigned short* w1t = (unsigned short*)(ws + ((size_t)177 << 20));
  unsigned short* w2t = (unsigned short*)(ws + ((size_t)178 << 20));
  char* sb = ws + ((size_t)180 << 20);
  float* gatev = (float*)sb;                                        // 128 KiB
  int* topidx = (int*)(sb + 131072);                                // 16 KiB
  float* hlast = (float*)(sb + 131072 + 16384);                     // 32 KiB
  float* ctxbuf = (float*)(sb + 131072 + 16384 + 32768);            // 32 KiB
  float* qpart = (float*)(sb + 131072 + 16384 + 65536);             // 256 KiB

  hipFuncSetAttribute(reinterpret_cast<const void*>(gemm256_kernel<512, 1024, 4, true>),
                      hipFuncAttributeMaxDynamicSharedMemorySize, 131072);
  hipFuncSetAttribute(reinterpret_cast<const void*>(gemm256_kernel<1024, 512, 2, false>),
                      hipFuncAttributeMaxDynamicSharedMemorySize, 131072);

  cvtwt_kernel<<<12096, 256, 0, stream>>>(emb, embb, w1, w2, w1t, w2t);
  gemm256_kernel<512, 1024, 4, true>
      <<<500, 512, 131072, stream>>>(embb, w1t, b1, A1v);
  gemm256_kernel<1024, 512, 2, false>
      <<<250, 512, 131072, stream>>>(A1v, w2t, b2, FFv);
  lnv_kernel<<<8000, 256, 0, stream>>>(emb, FFv, Hv, ln_g, ln_b, wg, bg, gatev, seq, hlast);
  topk_qpart_kernel<<<144, 256, 0, stream>>>(gatev, seq, topidx, hlast, wq, bq, qpart);
  attn_kernel<<<64, 256, 0, stream>>>(Hv, seq, qpart, topidx, ctxbuf);
  out_part_kernel<<<1000, 256, 0, stream>>>(ctxbuf, wo, part);
  out_reduce_kernel<<<2000, 256, 0, stream>>>(part, bo, out);
}